// Round 1
// baseline (3368.248 us; speedup 1.0000x reference)
//
#include <hip/hip_runtime.h>

static constexpr int N0 = 50000;
static constexpr int N1 = 200000;
static constexpr int N2 = 100000;
static constexpr int NNZ0 = 600000;
static constexpr int NNZ1 = 1000000;
static constexpr int NNZ2 = 600000;
static constexpr int FIN = 500;
static constexpr int KP = 512;   // padded K for MFMA (16 chunks of 32)

typedef __attribute__((ext_vector_type(8))) short bf16x8;
typedef __attribute__((ext_vector_type(4))) float f32x4;

__device__ __forceinline__ unsigned short f2bf(float f) {
  unsigned int b = __float_as_uint(f);
  b = (b + 0x7FFFu + ((b >> 16) & 1u)) >> 16;   // RNE
  return (unsigned short)b;
}

// ---------- pack X0 -> binarized bf16, padded to 512 cols ----------
__global__ void pack_x_kernel(const float* __restrict__ X0, unsigned short* __restrict__ Xb) {
  int g = blockIdx.x * 256 + threadIdx.x;
  if (g >= N0 * KP) return;
  int c = g & (KP - 1);
  int r = g >> 9;
  unsigned short v = 0;
  if (c < FIN) v = (X0[(long long)r * FIN + c] != 0.0f) ? (unsigned short)0x3F80u : (unsigned short)0u;
  Xb[g] = v;
}

// ---------- pack W -> bf16 MFMA B-fragment layout: [level][kc][nb][lane][j] ----------
// element = W[2*level + (col128>>6)][k = kc*32 + (lane>>4)*8 + j][col128 & 63], col128 = nb*16 + (lane&15)
__global__ void pack_w_kernel(const float* __restrict__ W, unsigned short* __restrict__ Bp) {
  int g = blockIdx.x * 256 + threadIdx.x;
  if (g >= 3 * 65536) return;
  int j = g & 7;
  int lane = (g >> 3) & 63;
  int nb = (g >> 9) & 7;
  int kc = (g >> 12) & 15;
  int level = g >> 16;
  int k = kc * 32 + (lane >> 4) * 8 + j;
  int col128 = nb * 16 + (lane & 15);
  int head = level * 2 + (col128 >> 6);
  int col = col128 & 63;
  float f = 0.0f;
  if (k < FIN) f = W[((long long)head * FIN + k) * 64 + col];
  Bp[g] = f2bf(f);
}

// ---------- fused gather(AND) + GEMM + bias + s2 epilogue ----------
// Tile: 64 rows x 128 cols (two heads x 64), K = 512. Block = 4 waves, wave w -> rows 16w..16w+15.
template <int NSRC>
__global__ __launch_bounds__(256) void gemm_sat_kernel(
    const unsigned short* __restrict__ Xb, const int* __restrict__ srcidx,
    const unsigned short* __restrict__ Bp, const float* __restrict__ bvec,
    const float* __restrict__ a2w, const float* __restrict__ a2b, int head_lo,
    int M, float* __restrict__ h_lo, float* __restrict__ h_hi,
    float* __restrict__ s2_lo, float* __restrict__ s2_hi) {
  __shared__ __align__(16) unsigned short As[64 * 520];   // +8 pad breaks LDS bank stride
  const int tid = threadIdx.x;
  const int m0 = blockIdx.x * 64;
  {
    int r = tid >> 2;            // row in tile
    int q = tid & 3;             // column quarter (128 cols each)
    int rg = m0 + r;
    bool valid = rg < M;
    const uint4* up = nullptr; const uint4* vp = nullptr; const uint4* wp = nullptr;
    if (valid) {
      if (NSRC == 1) {
        up = (const uint4*)(Xb + (long long)rg * KP);
      } else if (NSRC == 2) {
        up = (const uint4*)(Xb + (long long)srcidx[2 * rg + 0] * KP);
        vp = (const uint4*)(Xb + (long long)srcidx[2 * rg + 1] * KP);
      } else {
        up = (const uint4*)(Xb + (long long)srcidx[3 * rg + 0] * KP);
        vp = (const uint4*)(Xb + (long long)srcidx[3 * rg + 1] * KP);
        wp = (const uint4*)(Xb + (long long)srcidx[3 * rg + 2] * KP);
      }
    }
#pragma unroll 4
    for (int i = 0; i < 16; ++i) {
      int vi = q * 16 + i;       // uint4 index within the row (8 bf16 each)
      uint4 a = make_uint4(0u, 0u, 0u, 0u);
      if (valid) {
        a = up[vi];
        if (NSRC >= 2) { uint4 bv = vp[vi]; a.x &= bv.x; a.y &= bv.y; a.z &= bv.z; a.w &= bv.w; }
        if (NSRC == 3) { uint4 cv = wp[vi]; a.x &= cv.x; a.y &= cv.y; a.z &= cv.z; a.w &= cv.w; }
      }
      *(uint4*)(&As[r * 520 + vi * 8]) = a;   // bf16 0/1 product == bitwise AND (exact)
    }
  }
  __syncthreads();

  const int wave = tid >> 6;
  const int lane = tid & 63;
  const int quad = lane >> 4;
  const int l16 = lane & 15;
  f32x4 acc[8];
#pragma unroll
  for (int i = 0; i < 8; ++i) acc[i] = (f32x4){0.f, 0.f, 0.f, 0.f};
  const unsigned short* arow = &As[(wave * 16 + l16) * 520 + quad * 8];
  const bf16x8* Bf = (const bf16x8*)Bp;
#pragma unroll 4
  for (int kc = 0; kc < 16; ++kc) {
    bf16x8 af = *(const bf16x8*)(arow + kc * 32);   // A[m=l16][k=kc*32+quad*8+j]
#pragma unroll
    for (int nb = 0; nb < 8; ++nb) {
      bf16x8 bf = Bf[(kc * 8 + nb) * 64 + lane];    // B[k][n=l16] packed contiguous per lane
      acc[nb] = __builtin_amdgcn_mfma_f32_16x16x32_bf16(af, bf, acc[nb], 0, 0, 0);
    }
  }

  // epilogue: bias add, store h, and s2 = h . a2w + a2b via 16-lane reduce
  float plo[4] = {0.f, 0.f, 0.f, 0.f};
  float phi[4] = {0.f, 0.f, 0.f, 0.f};
#pragma unroll
  for (int nb = 0; nb < 8; ++nb) {
    int col128 = nb * 16 + l16;
    int hh = col128 >> 6;
    int col = col128 & 63;
    float bia = bvec[(head_lo + hh) * 64 + col];
    float aw = a2w[(head_lo + hh) * 64 + col];
    float* hdst = hh ? h_hi : h_lo;
#pragma unroll
    for (int reg = 0; reg < 4; ++reg) {
      int rg = m0 + wave * 16 + quad * 4 + reg;     // C/D: row=quad*4+reg, col=l16 (m89-verified)
      float v = acc[nb][reg] + bia;
      if (rg < M) hdst[(long long)rg * 64 + col] = v;
      if (hh) phi[reg] += v * aw; else plo[reg] += v * aw;
    }
  }
#pragma unroll
  for (int off = 1; off < 16; off <<= 1) {
#pragma unroll
    for (int reg = 0; reg < 4; ++reg) {
      plo[reg] += __shfl_xor(plo[reg], off);
      phi[reg] += __shfl_xor(phi[reg], off);
    }
  }
  if (l16 == 0) {
    float blo = a2b[head_lo];
    float bhi = a2b[head_lo + 1];
#pragma unroll
    for (int reg = 0; reg < 4; ++reg) {
      int rg = m0 + wave * 16 + quad * 4 + reg;
      if (rg < M) { s2_lo[rg] = plo[reg] + blo; s2_hi[rg] = phi[reg] + bhi; }
    }
  }
}

// ---------- CSR build ----------
__global__ void count_rows_kernel(const int* __restrict__ rows, int* __restrict__ cnt, int nnz) {
  int g = blockIdx.x * 256 + threadIdx.x;
  if (g < nnz) atomicAdd(&cnt[rows[g]], 1);
}

__global__ void exscan_kernel(const int* __restrict__ cnt, int* __restrict__ rowptr, int n) {
  __shared__ int sums[1024];
  int t = threadIdx.x;
  int chunk = (n + 1023) >> 10;
  int s0 = t * chunk;
  int s1 = s0 + chunk; if (s1 > n) s1 = n;
  int s = 0;
  for (int i = s0; i < s1; ++i) s += cnt[i];
  sums[t] = s;
  __syncthreads();
  for (int off = 1; off < 1024; off <<= 1) {
    int v = (t >= off) ? sums[t - off] : 0;
    __syncthreads();
    sums[t] += v;
    __syncthreads();
  }
  int base = (t == 0) ? 0 : sums[t - 1];
  for (int i = s0; i < s1; ++i) { rowptr[i] = base; base += cnt[i]; }
  if (t == 1023) rowptr[n] = sums[1023];
}

__global__ void fill_csr_kernel(const int* __restrict__ rows, const int* __restrict__ cols,
                                const int* __restrict__ rowptr, int* __restrict__ cur,
                                int* __restrict__ outcol, int nnz) {
  int g = blockIdx.x * 256 + threadIdx.x;
  if (g >= nnz) return;
  int r = rows[g];
  int pos = rowptr[r] + atomicAdd(&cur[r], 1);
  outcol[pos] = cols ? cols[g] : g;   // SAT matrices store col; B1/B2 store entry id
}

// ---------- SAT: wave per row, lane = dim. s1 cancels; softmax over s2[c] only ----------
__global__ __launch_bounds__(256) void sat_dual_kernel(
    const int* __restrict__ rowptr, const int* __restrict__ col,
    const float* __restrict__ s2a, const float* __restrict__ ha,
    const float* __restrict__ s2b, const float* __restrict__ hb,
    const float* __restrict__ pw, float* __restrict__ out, int n) {
  int row = blockIdx.x * 4 + (threadIdx.x >> 6);
  if (row >= n) return;
  int lane = threadIdx.x & 63;
  int p0 = rowptr[row], p1 = rowptr[row + 1];
  float ma = -3.0e38f, mb = -3.0e38f;
  for (int p = p0 + lane; p < p1; p += 64) {
    int c = col[p];
    ma = fmaxf(ma, s2a[c]); mb = fmaxf(mb, s2b[c]);
  }
#pragma unroll
  for (int off = 32; off > 0; off >>= 1) {
    ma = fmaxf(ma, __shfl_xor(ma, off)); mb = fmaxf(mb, __shfl_xor(mb, off));
  }
  float za = 0.f, zb = 0.f;
  for (int p = p0 + lane; p < p1; p += 64) {
    int c = col[p];
    za += __expf(s2a[c] - ma); zb += __expf(s2b[c] - mb);
  }
#pragma unroll
  for (int off = 32; off > 0; off >>= 1) {
    za += __shfl_xor(za, off); zb += __shfl_xor(zb, off);
  }
  float ia = (p1 > p0) ? 1.f / za : 0.f;
  float ib = (p1 > p0) ? 1.f / zb : 0.f;
  float acc = 0.f;
  for (int p = p0; p < p1; ++p) {
    int c = col[p];
    float wa = __expf(s2a[c] - ma) * ia;
    float wb = __expf(s2b[c] - mb) * ib;
    acc += wa * ha[(long long)c * 64 + lane] + wb * hb[(long long)c * 64 + lane];
  }
  float pv = pw[0];
  out[(long long)row * 64 + lane] = acc >= 0.f ? acc : pv * acc;   // prelu fused
}

template <bool ADD>
__global__ __launch_bounds__(256) void sat_single_kernel(
    const int* __restrict__ rowptr, const int* __restrict__ col,
    const float* __restrict__ s2, const float* __restrict__ h,
    float* __restrict__ out, int n) {
  int row = blockIdx.x * 4 + (threadIdx.x >> 6);
  if (row >= n) return;
  int lane = threadIdx.x & 63;
  int p0 = rowptr[row], p1 = rowptr[row + 1];
  float m = -3.0e38f;
  for (int p = p0 + lane; p < p1; p += 64) m = fmaxf(m, s2[col[p]]);
#pragma unroll
  for (int off = 32; off > 0; off >>= 1) m = fmaxf(m, __shfl_xor(m, off));
  float z = 0.f;
  for (int p = p0 + lane; p < p1; p += 64) z += __expf(s2[col[p]] - m);
#pragma unroll
  for (int off = 32; off > 0; off >>= 1) z += __shfl_xor(z, off);
  float iz = (p1 > p0) ? 1.f / z : 0.f;
  float acc = 0.f;
  for (int p = p0; p < p1; ++p) {
    int c = col[p];
    acc += (__expf(s2[c] - m) * iz) * h[(long long)c * 64 + lane];
  }
  long long oi = (long long)row * 64 + lane;
  if (ADD) out[oi] += acc; else out[oi] = acc;
}

__global__ void prelu_kernel(float* __restrict__ x, const float* __restrict__ pw, int n) {
  int g = blockIdx.x * 256 + threadIdx.x;
  if (g < n) { float v = x[g]; x[g] = v >= 0.f ? v : pw[0] * v; }
}

// ---------- Tm_pre = B2 @ H2 (CSR of B2 rows; col = e/3, val = +1,-1,+1 pattern) ----------
__global__ __launch_bounds__(256) void spmm_b2_kernel(
    const int* __restrict__ rowptr, const int* __restrict__ ent,
    const float* __restrict__ H2, float* __restrict__ Tm, int n) {
  int row = blockIdx.x * 4 + (threadIdx.x >> 6);
  if (row >= n) return;
  int lane = threadIdx.x & 63;
  int p0 = rowptr[row], p1 = rowptr[row + 1];
  float acc = 0.f;
  for (int p = p0; p < p1; ++p) {
    int e = ent[p];
    int c = e / 3;
    float s = (e - 3 * c == 1) ? -1.f : 1.f;
    acc += s * H2[(long long)c * 64 + lane];
  }
  Tm[(long long)row * 64 + lane] = acc;
}

// ---------- Tm = Tm_pre @ triW + trib, fp32, in place (row fully read before write) ----------
__global__ __launch_bounds__(256) void tri_gemm_kernel(float* __restrict__ Tm,
                                                       const float* __restrict__ triW,
                                                       const float* __restrict__ trib, int n) {
  __shared__ float Wl[64 * 64];
  for (int i = threadIdx.x; i < 64 * 64; i += 256) Wl[i] = triW[i];
  __syncthreads();
  int row = blockIdx.x * 4 + (threadIdx.x >> 6);
  if (row >= n) return;
  int lane = threadIdx.x & 63;
  float x = Tm[(long long)row * 64 + lane];
  float acc = trib[lane];
#pragma unroll
  for (int k = 0; k < 64; ++k) acc += __shfl(x, k) * Wl[k * 64 + lane];
  Tm[(long long)row * 64 + lane] = acc;
}

// ---------- out = (H0 + B1 @ (H1 + Tm)) / 3 ----------
__global__ __launch_bounds__(256) void final_kernel(
    const int* __restrict__ rowptr, const int* __restrict__ ent,
    const float* __restrict__ H0, const float* __restrict__ H1,
    const float* __restrict__ Tm, float* __restrict__ out, int n) {
  int row = blockIdx.x * 4 + (threadIdx.x >> 6);
  if (row >= n) return;
  int lane = threadIdx.x & 63;
  int p0 = rowptr[row], p1 = rowptr[row + 1];
  float acc = H0[(long long)row * 64 + lane];
  for (int p = p0; p < p1; ++p) {
    int e = ent[p];
    int c = e >> 1;                       // B1 col = edge id = e/2
    float s = (e & 1) ? -1.f : 1.f;       // B1 val pattern [+1,-1]
    acc += s * (H1[(long long)c * 64 + lane] + Tm[(long long)c * 64 + lane]);
  }
  out[(long long)row * 64 + lane] = acc * (1.0f / 3.0f);
}

extern "C" void kernel_launch(void* const* d_in, const int* in_sizes, int n_in,
                              void* d_out, int out_size, void* d_ws, size_t ws_size,
                              hipStream_t stream) {
  const float* X0 = (const float*)d_in[0];
  const int* E1 = (const int*)d_in[1];
  const int* T2 = (const int*)d_in[2];
  const int* L0i = (const int*)d_in[3];
  const int* L1ai = (const int*)d_in[4];
  const int* L1bi = (const int*)d_in[5];
  const int* L2i = (const int*)d_in[6];
  const int* B1i = (const int*)d_in[7];
  const int* B2i = (const int*)d_in[9];
  const float* W = (const float*)d_in[11];
  const float* bvec = (const float*)d_in[12];
  // a1_w/a1_b (d_in[13],[14]) are mathematically dead: s1[r] cancels in the row softmax.
  const float* a2w = (const float*)d_in[15];
  const float* a2b = (const float*)d_in[16];
  const float* pw = (const float*)d_in[17];
  const float* triW = (const float*)d_in[18];
  const float* trib = (const float*)d_in[19];
  float* out = (float*)d_out;

  char* base = (char*)d_ws;
  size_t off = 0;
  auto alloc = [&](size_t bytes) -> void* {
    void* p = base + off;
    off += (bytes + 255) & ~(size_t)255;
    return p;
  };
  unsigned short* Xb = (unsigned short*)alloc((size_t)N0 * KP * 2);
  unsigned short* Bp = (unsigned short*)alloc((size_t)3 * 65536 * 2);
  float* h0 = (float*)alloc((size_t)N0 * 64 * 4);
  float* h1 = (float*)alloc((size_t)N0 * 64 * 4);
  float* h2 = (float*)alloc((size_t)N1 * 64 * 4);
  float* h3 = (float*)alloc((size_t)N1 * 64 * 4);
  float* h4 = (float*)alloc((size_t)N2 * 64 * 4);   // h4+h5 contiguous: reused as Tm (N1 x 64)
  float* h5 = (float*)alloc((size_t)N2 * 64 * 4);
  float* Tm = h4;
  float* s2_0 = (float*)alloc((size_t)N0 * 4);
  float* s2_1 = (float*)alloc((size_t)N0 * 4);
  float* s2_2 = (float*)alloc((size_t)N1 * 4);
  float* s2_3 = (float*)alloc((size_t)N1 * 4);
  float* s2_4 = (float*)alloc((size_t)N2 * 4);
  float* s2_5 = (float*)alloc((size_t)N2 * 4);
  float* H0 = (float*)alloc((size_t)N0 * 64 * 4);
  float* H1 = (float*)alloc((size_t)N1 * 64 * 4);
  float* H2 = (float*)alloc((size_t)N2 * 64 * 4);
  int* rp0 = (int*)alloc((size_t)(N0 + 1) * 4);
  int* rp1a = (int*)alloc((size_t)(N1 + 1) * 4);
  int* rp1b = (int*)alloc((size_t)(N1 + 1) * 4);
  int* rp2 = (int*)alloc((size_t)(N2 + 1) * 4);
  int* rpB1 = (int*)alloc((size_t)(N0 + 1) * 4);
  int* rpB2 = (int*)alloc((size_t)(N1 + 1) * 4);
  int* c0 = (int*)alloc((size_t)NNZ0 * 4);
  int* c1a = (int*)alloc((size_t)NNZ1 * 4);
  int* c1b = (int*)alloc((size_t)NNZ1 * 4);
  int* c2 = (int*)alloc((size_t)NNZ2 * 4);
  int* eB1 = (int*)alloc((size_t)2 * N1 * 4);
  int* eB2 = (int*)alloc((size_t)3 * N2 * 4);
  int* cnt = (int*)alloc((size_t)800000 * 4);
  int* cur = (int*)alloc((size_t)800000 * 4);

  hipMemsetAsync(cnt, 0, (size_t)800000 * 4, stream);
  hipMemsetAsync(cur, 0, (size_t)800000 * 4, stream);

  pack_x_kernel<<<(N0 * KP + 255) / 256, 256, 0, stream>>>(X0, Xb);
  pack_w_kernel<<<(3 * 65536 + 255) / 256, 256, 0, stream>>>(W, Bp);

  gemm_sat_kernel<1><<<(N0 + 63) / 64, 256, 0, stream>>>(Xb, nullptr, Bp, bvec, a2w, a2b, 0, N0, h0, h1, s2_0, s2_1);
  gemm_sat_kernel<2><<<(N1 + 63) / 64, 256, 0, stream>>>(Xb, E1, Bp + 65536, bvec, a2w, a2b, 2, N1, h2, h3, s2_2, s2_3);
  gemm_sat_kernel<3><<<(N2 + 63) / 64, 256, 0, stream>>>(Xb, T2, Bp + 2 * 65536, bvec, a2w, a2b, 4, N2, h4, h5, s2_4, s2_5);

  int* cntL0 = cnt + 0;       int* curL0 = cur + 0;
  int* cntL1a = cnt + 50000;  int* curL1a = cur + 50000;
  int* cntL1b = cnt + 250000; int* curL1b = cur + 250000;
  int* cntL2 = cnt + 450000;  int* curL2 = cur + 450000;
  int* cntB1 = cnt + 550000;  int* curB1 = cur + 550000;
  int* cntB2 = cnt + 600000;  int* curB2 = cur + 600000;

  count_rows_kernel<<<(NNZ0 + 255) / 256, 256, 0, stream>>>(L0i, cntL0, NNZ0);
  exscan_kernel<<<1, 1024, 0, stream>>>(cntL0, rp0, N0);
  fill_csr_kernel<<<(NNZ0 + 255) / 256, 256, 0, stream>>>(L0i, L0i + NNZ0, rp0, curL0, c0, NNZ0);

  count_rows_kernel<<<(NNZ1 + 255) / 256, 256, 0, stream>>>(L1ai, cntL1a, NNZ1);
  exscan_kernel<<<1, 1024, 0, stream>>>(cntL1a, rp1a, N1);
  fill_csr_kernel<<<(NNZ1 + 255) / 256, 256, 0, stream>>>(L1ai, L1ai + NNZ1, rp1a, curL1a, c1a, NNZ1);

  count_rows_kernel<<<(NNZ1 + 255) / 256, 256, 0, stream>>>(L1bi, cntL1b, NNZ1);
  exscan_kernel<<<1, 1024, 0, stream>>>(cntL1b, rp1b, N1);
  fill_csr_kernel<<<(NNZ1 + 255) / 256, 256, 0, stream>>>(L1bi, L1bi + NNZ1, rp1b, curL1b, c1b, NNZ1);

  count_rows_kernel<<<(NNZ2 + 255) / 256, 256, 0, stream>>>(L2i, cntL2, NNZ2);
  exscan_kernel<<<1, 1024, 0, stream>>>(cntL2, rp2, N2);
  fill_csr_kernel<<<(NNZ2 + 255) / 256, 256, 0, stream>>>(L2i, L2i + NNZ2, rp2, curL2, c2, NNZ2);

  count_rows_kernel<<<(2 * N1 + 255) / 256, 256, 0, stream>>>(B1i, cntB1, 2 * N1);
  exscan_kernel<<<1, 1024, 0, stream>>>(cntB1, rpB1, N0);
  fill_csr_kernel<<<(2 * N1 + 255) / 256, 256, 0, stream>>>(B1i, nullptr, rpB1, curB1, eB1, 2 * N1);

  count_rows_kernel<<<(3 * N2 + 255) / 256, 256, 0, stream>>>(B2i, cntB2, 3 * N2);
  exscan_kernel<<<1, 1024, 0, stream>>>(cntB2, rpB2, N1);
  fill_csr_kernel<<<(3 * N2 + 255) / 256, 256, 0, stream>>>(B2i, nullptr, rpB2, curB2, eB2, 3 * N2);

  sat_dual_kernel<<<(N0 + 3) / 4, 256, 0, stream>>>(rp0, c0, s2_0, h0, s2_1, h1, pw, H0, N0);
  sat_single_kernel<false><<<(N1 + 3) / 4, 256, 0, stream>>>(rp1a, c1a, s2_2, h2, H1, N1);
  sat_single_kernel<true><<<(N1 + 3) / 4, 256, 0, stream>>>(rp1b, c1b, s2_3, h3, H1, N1);
  prelu_kernel<<<(N1 * 64 + 255) / 256, 256, 0, stream>>>(H1, pw, N1 * 64);
  sat_dual_kernel<<<(N2 + 3) / 4, 256, 0, stream>>>(rp2, c2, s2_4, h4, s2_5, h5, pw, H2, N2);

  spmm_b2_kernel<<<(N1 + 3) / 4, 256, 0, stream>>>(rpB2, eB2, H2, Tm, N1);   // h4/h5 dead now
  tri_gemm_kernel<<<(N1 + 3) / 4, 256, 0, stream>>>(Tm, triW, trib, N1);
  final_kernel<<<(N0 + 3) / 4, 256, 0, stream>>>(rpB1, eB1, H0, H1, Tm, out, N0);
}

// Round 2
// 2118.909 us; speedup vs baseline: 1.5896x; 1.5896x over previous
//
#include <hip/hip_runtime.h>

static constexpr int N0 = 50000;
static constexpr int N1 = 200000;
static constexpr int N2 = 100000;
static constexpr int NNZ0 = 600000;
static constexpr int NNZ1 = 1000000;
static constexpr int NNZ2 = 600000;
static constexpr int FIN = 500;
static constexpr int KP = 512;   // padded K for MFMA (16 chunks of 32)

// concatenated count layout: [L0 | L1a | L1b | L2 | B1 | B2]
static constexpr int SEG_L0 = 0;
static constexpr int SEG_L1A = 50000;
static constexpr int SEG_L1B = 250000;
static constexpr int SEG_L2 = 450000;
static constexpr int SEG_B1 = 550000;
static constexpr int SEG_B2 = 600000;
static constexpr int CNT_TOT = 800000;
static constexpr int POOL_TOT = NNZ0 + NNZ1 + NNZ1 + NNZ2 + 2 * N1 + 3 * N2;  // 3.9M
static constexpr int SCAN_CHUNK = 4096;                                        // per block
static constexpr int SCAN_BLOCKS = (CNT_TOT + SCAN_CHUNK - 1) / SCAN_CHUNK;    // 196

typedef __attribute__((ext_vector_type(8))) short bf16x8;
typedef __attribute__((ext_vector_type(4))) float f32x4;

__device__ __forceinline__ unsigned short f2bf(float f) {
  unsigned int b = __float_as_uint(f);
  b = (b + 0x7FFFu + ((b >> 16) & 1u)) >> 16;   // RNE
  return (unsigned short)b;
}

// ---------- pack X0 -> binarized bf16, padded to 512 cols ----------
__global__ void pack_x_kernel(const float* __restrict__ X0, unsigned short* __restrict__ Xb) {
  int g = blockIdx.x * 256 + threadIdx.x;
  if (g >= N0 * KP) return;
  int c = g & (KP - 1);
  int r = g >> 9;
  unsigned short v = 0;
  if (c < FIN) v = (X0[(long long)r * FIN + c] != 0.0f) ? (unsigned short)0x3F80u : (unsigned short)0u;
  Xb[g] = v;
}

// ---------- pack W -> bf16 MFMA B-fragment layout: [level][kc][nb][lane][j] ----------
__global__ void pack_w_kernel(const float* __restrict__ W, unsigned short* __restrict__ Bp) {
  int g = blockIdx.x * 256 + threadIdx.x;
  if (g >= 3 * 65536) return;
  int j = g & 7;
  int lane = (g >> 3) & 63;
  int nb = (g >> 9) & 7;
  int kc = (g >> 12) & 15;
  int level = g >> 16;
  int k = kc * 32 + (lane >> 4) * 8 + j;
  int col128 = nb * 16 + (lane & 15);
  int head = level * 2 + (col128 >> 6);
  int col = col128 & 63;
  float f = 0.0f;
  if (k < FIN) f = W[((long long)head * FIN + k) * 64 + col];
  Bp[g] = f2bf(f);
}

// ---------- fused gather(AND) + GEMM + bias + s2 epilogue ----------
template <int NSRC>
__global__ __launch_bounds__(256) void gemm_sat_kernel(
    const unsigned short* __restrict__ Xb, const int* __restrict__ srcidx,
    const unsigned short* __restrict__ Bp, const float* __restrict__ bvec,
    const float* __restrict__ a2w, const float* __restrict__ a2b, int head_lo,
    int M, float* __restrict__ h_lo, float* __restrict__ h_hi,
    float* __restrict__ s2_lo, float* __restrict__ s2_hi) {
  __shared__ __align__(16) unsigned short As[64 * 520];
  const int tid = threadIdx.x;
  const int m0 = blockIdx.x * 64;
  {
    int r = tid >> 2;
    int q = tid & 3;
    int rg = m0 + r;
    bool valid = rg < M;
    const uint4* up = nullptr; const uint4* vp = nullptr; const uint4* wp = nullptr;
    if (valid) {
      if (NSRC == 1) {
        up = (const uint4*)(Xb + (long long)rg * KP);
      } else if (NSRC == 2) {
        up = (const uint4*)(Xb + (long long)srcidx[2 * rg + 0] * KP);
        vp = (const uint4*)(Xb + (long long)srcidx[2 * rg + 1] * KP);
      } else {
        up = (const uint4*)(Xb + (long long)srcidx[3 * rg + 0] * KP);
        vp = (const uint4*)(Xb + (long long)srcidx[3 * rg + 1] * KP);
        wp = (const uint4*)(Xb + (long long)srcidx[3 * rg + 2] * KP);
      }
    }
#pragma unroll 4
    for (int i = 0; i < 16; ++i) {
      int vi = q * 16 + i;
      uint4 a = make_uint4(0u, 0u, 0u, 0u);
      if (valid) {
        a = up[vi];
        if (NSRC >= 2) { uint4 bv = vp[vi]; a.x &= bv.x; a.y &= bv.y; a.z &= bv.z; a.w &= bv.w; }
        if (NSRC == 3) { uint4 cv = wp[vi]; a.x &= cv.x; a.y &= cv.y; a.z &= cv.z; a.w &= cv.w; }
      }
      *(uint4*)(&As[r * 520 + vi * 8]) = a;   // bf16 0/1 product == bitwise AND (exact)
    }
  }
  __syncthreads();

  const int wave = tid >> 6;
  const int lane = tid & 63;
  const int quad = lane >> 4;
  const int l16 = lane & 15;
  f32x4 acc[8];
#pragma unroll
  for (int i = 0; i < 8; ++i) acc[i] = (f32x4){0.f, 0.f, 0.f, 0.f};
  const unsigned short* arow = &As[(wave * 16 + l16) * 520 + quad * 8];
  const bf16x8* Bf = (const bf16x8*)Bp;
#pragma unroll 4
  for (int kc = 0; kc < 16; ++kc) {
    bf16x8 af = *(const bf16x8*)(arow + kc * 32);
#pragma unroll
    for (int nb = 0; nb < 8; ++nb) {
      bf16x8 bf = Bf[(kc * 8 + nb) * 64 + lane];
      acc[nb] = __builtin_amdgcn_mfma_f32_16x16x32_bf16(af, bf, acc[nb], 0, 0, 0);
    }
  }

  float plo[4] = {0.f, 0.f, 0.f, 0.f};
  float phi[4] = {0.f, 0.f, 0.f, 0.f};
#pragma unroll
  for (int nb = 0; nb < 8; ++nb) {
    int col128 = nb * 16 + l16;
    int hh = col128 >> 6;
    int col = col128 & 63;
    float bia = bvec[(head_lo + hh) * 64 + col];
    float aw = a2w[(head_lo + hh) * 64 + col];
    float* hdst = hh ? h_hi : h_lo;
#pragma unroll
    for (int reg = 0; reg < 4; ++reg) {
      int rg = m0 + wave * 16 + quad * 4 + reg;     // C/D: row=quad*4+reg, col=l16
      float v = acc[nb][reg] + bia;
      if (rg < M) hdst[(long long)rg * 64 + col] = v;
      if (hh) phi[reg] += v * aw; else plo[reg] += v * aw;
    }
  }
#pragma unroll
  for (int off = 1; off < 16; off <<= 1) {
#pragma unroll
    for (int reg = 0; reg < 4; ++reg) {
      plo[reg] += __shfl_xor(plo[reg], off);
      phi[reg] += __shfl_xor(phi[reg], off);
    }
  }
  if (l16 == 0) {
    float blo = a2b[head_lo];
    float bhi = a2b[head_lo + 1];
#pragma unroll
    for (int reg = 0; reg < 4; ++reg) {
      int rg = m0 + wave * 16 + quad * 4 + reg;
      if (rg < M) { s2_lo[rg] = plo[reg] + blo; s2_hi[rg] = phi[reg] + bhi; }
    }
  }
}

// ---------- CSR build: histogram + 3-phase global scan + cursor fill ----------
__global__ void count_rows_kernel(const int* __restrict__ rows, int* __restrict__ cnt, int nnz) {
  int g = blockIdx.x * 256 + threadIdx.x;
  if (g < nnz) atomicAdd(&cnt[rows[g]], 1);
}

// phase 1: per-block sums of 4096-element chunks
__global__ __launch_bounds__(256) void scan_partial_kernel(const int* __restrict__ cnt,
                                                           int* __restrict__ bsum) {
  __shared__ int s[256];
  int b = blockIdx.x, t = threadIdx.x;
  int base = b * SCAN_CHUNK + t * 16;
  int sum = 0;
#pragma unroll
  for (int i = 0; i < 16; ++i) {
    int idx = base + i;
    if (idx < CNT_TOT) sum += cnt[idx];
  }
  s[t] = sum;
  __syncthreads();
  for (int off = 128; off > 0; off >>= 1) {
    if (t < off) s[t] += s[t + off];
    __syncthreads();
  }
  if (t == 0) bsum[b] = s[0];
}

// phase 2: exclusive scan of block sums (<=256) in one block; bsum[nb] = grand total
__global__ __launch_bounds__(256) void scan_bsum_kernel(int* __restrict__ bsum, int nb) {
  __shared__ int s[256];
  int t = threadIdx.x;
  int v = (t < nb) ? bsum[t] : 0;
  s[t] = v;
  __syncthreads();
  for (int off = 1; off < 256; off <<= 1) {
    int u = (t >= off) ? s[t - off] : 0;
    __syncthreads();
    s[t] += u;
    __syncthreads();
  }
  if (t < nb) bsum[t] = (t == 0) ? 0 : s[t - 1];
  if (t == 0) bsum[nb] = s[nb - 1];
}

// phase 3: per-block exclusive scan + block offset -> global exclusive scan
__global__ __launch_bounds__(256) void scan_write_kernel(const int* __restrict__ cnt,
                                                         const int* __restrict__ bsum,
                                                         int* __restrict__ gscan) {
  __shared__ int s[256];
  int b = blockIdx.x, t = threadIdx.x;
  int base = b * SCAN_CHUNK + t * 16;
  int loc[16];
  int sum = 0;
#pragma unroll
  for (int i = 0; i < 16; ++i) {
    int idx = base + i;
    int v = (idx < CNT_TOT) ? cnt[idx] : 0;
    loc[i] = sum;
    sum += v;
  }
  s[t] = sum;
  __syncthreads();
  for (int off = 1; off < 256; off <<= 1) {
    int u = (t >= off) ? s[t - off] : 0;
    __syncthreads();
    s[t] += u;
    __syncthreads();
  }
  int toff = bsum[b] + ((t == 0) ? 0 : s[t - 1]);
#pragma unroll
  for (int i = 0; i < 16; ++i) {
    int idx = base + i;
    if (idx < CNT_TOT) gscan[idx] = toff + loc[i];
  }
  if (b == 0 && t == 0) gscan[CNT_TOT] = bsum[SCAN_BLOCKS];
}

__global__ void fill_csr_kernel(const int* __restrict__ rows, const int* __restrict__ cols,
                                const int* __restrict__ rowptr, int* __restrict__ cur,
                                int* __restrict__ pool, int nnz) {
  int g = blockIdx.x * 256 + threadIdx.x;
  if (g >= nnz) return;
  int r = rows[g];
  int pos = rowptr[r] + atomicAdd(&cur[r], 1);   // rowptr is absolute into pool
  pool[pos] = cols ? cols[g] : g;                // SAT: col; B1/B2: entry id
}

// ---------- SAT: wave per row, lane = dim. s1 cancels; softmax over s2[c] only ----------
__global__ __launch_bounds__(256) void sat_dual_kernel(
    const int* __restrict__ rowptr, const int* __restrict__ col,
    const float* __restrict__ s2a, const float* __restrict__ ha,
    const float* __restrict__ s2b, const float* __restrict__ hb,
    const float* __restrict__ pw, float* __restrict__ out, int n) {
  int row = blockIdx.x * 4 + (threadIdx.x >> 6);
  if (row >= n) return;
  int lane = threadIdx.x & 63;
  int p0 = rowptr[row], p1 = rowptr[row + 1];
  float ma = -3.0e38f, mb = -3.0e38f;
  for (int p = p0 + lane; p < p1; p += 64) {
    int c = col[p];
    ma = fmaxf(ma, s2a[c]); mb = fmaxf(mb, s2b[c]);
  }
#pragma unroll
  for (int off = 32; off > 0; off >>= 1) {
    ma = fmaxf(ma, __shfl_xor(ma, off)); mb = fmaxf(mb, __shfl_xor(mb, off));
  }
  float za = 0.f, zb = 0.f;
  for (int p = p0 + lane; p < p1; p += 64) {
    int c = col[p];
    za += __expf(s2a[c] - ma); zb += __expf(s2b[c] - mb);
  }
#pragma unroll
  for (int off = 32; off > 0; off >>= 1) {
    za += __shfl_xor(za, off); zb += __shfl_xor(zb, off);
  }
  float ia = (p1 > p0) ? 1.f / za : 0.f;
  float ib = (p1 > p0) ? 1.f / zb : 0.f;
  float acc = 0.f;
  for (int p = p0; p < p1; ++p) {
    int c = col[p];
    float wa = __expf(s2a[c] - ma) * ia;
    float wb = __expf(s2b[c] - mb) * ib;
    acc += wa * ha[(long long)c * 64 + lane] + wb * hb[(long long)c * 64 + lane];
  }
  float pv = pw[0];
  out[(long long)row * 64 + lane] = acc >= 0.f ? acc : pv * acc;   // prelu fused
}

template <bool ADD>
__global__ __launch_bounds__(256) void sat_single_kernel(
    const int* __restrict__ rowptr, const int* __restrict__ col,
    const float* __restrict__ s2, const float* __restrict__ h,
    float* __restrict__ out, int n) {
  int row = blockIdx.x * 4 + (threadIdx.x >> 6);
  if (row >= n) return;
  int lane = threadIdx.x & 63;
  int p0 = rowptr[row], p1 = rowptr[row + 1];
  float m = -3.0e38f;
  for (int p = p0 + lane; p < p1; p += 64) m = fmaxf(m, s2[col[p]]);
#pragma unroll
  for (int off = 32; off > 0; off >>= 1) m = fmaxf(m, __shfl_xor(m, off));
  float z = 0.f;
  for (int p = p0 + lane; p < p1; p += 64) z += __expf(s2[col[p]] - m);
#pragma unroll
  for (int off = 32; off > 0; off >>= 1) z += __shfl_xor(z, off);
  float iz = (p1 > p0) ? 1.f / z : 0.f;
  float acc = 0.f;
  for (int p = p0; p < p1; ++p) {
    int c = col[p];
    acc += (__expf(s2[c] - m) * iz) * h[(long long)c * 64 + lane];
  }
  long long oi = (long long)row * 64 + lane;
  if (ADD) out[oi] += acc; else out[oi] = acc;
}

__global__ void prelu_kernel(float* __restrict__ x, const float* __restrict__ pw, int n) {
  int g = blockIdx.x * 256 + threadIdx.x;
  if (g < n) { float v = x[g]; x[g] = v >= 0.f ? v : pw[0] * v; }
}

// ---------- Tm_pre = B2 @ H2 ----------
__global__ __launch_bounds__(256) void spmm_b2_kernel(
    const int* __restrict__ rowptr, const int* __restrict__ ent,
    const float* __restrict__ H2, float* __restrict__ Tm, int n) {
  int row = blockIdx.x * 4 + (threadIdx.x >> 6);
  if (row >= n) return;
  int lane = threadIdx.x & 63;
  int p0 = rowptr[row], p1 = rowptr[row + 1];
  float acc = 0.f;
  for (int p = p0; p < p1; ++p) {
    int e = ent[p];
    int c = e / 3;
    float s = (e - 3 * c == 1) ? -1.f : 1.f;
    acc += s * H2[(long long)c * 64 + lane];
  }
  Tm[(long long)row * 64 + lane] = acc;
}

// ---------- Tm = Tm_pre @ triW + trib ----------
__global__ __launch_bounds__(256) void tri_gemm_kernel(float* __restrict__ Tm,
                                                       const float* __restrict__ triW,
                                                       const float* __restrict__ trib, int n) {
  __shared__ float Wl[64 * 64];
  for (int i = threadIdx.x; i < 64 * 64; i += 256) Wl[i] = triW[i];
  __syncthreads();
  int row = blockIdx.x * 4 + (threadIdx.x >> 6);
  if (row >= n) return;
  int lane = threadIdx.x & 63;
  float x = Tm[(long long)row * 64 + lane];
  float acc = trib[lane];
#pragma unroll
  for (int k = 0; k < 64; ++k) acc += __shfl(x, k) * Wl[k * 64 + lane];
  Tm[(long long)row * 64 + lane] = acc;
}

// ---------- out = (H0 + B1 @ (H1 + Tm)) / 3 ----------
__global__ __launch_bounds__(256) void final_kernel(
    const int* __restrict__ rowptr, const int* __restrict__ ent,
    const float* __restrict__ H0, const float* __restrict__ H1,
    const float* __restrict__ Tm, float* __restrict__ out, int n) {
  int row = blockIdx.x * 4 + (threadIdx.x >> 6);
  if (row >= n) return;
  int lane = threadIdx.x & 63;
  int p0 = rowptr[row], p1 = rowptr[row + 1];
  float acc = H0[(long long)row * 64 + lane];
  for (int p = p0; p < p1; ++p) {
    int e = ent[p];
    int c = e >> 1;
    float s = (e & 1) ? -1.f : 1.f;
    acc += s * (H1[(long long)c * 64 + lane] + Tm[(long long)c * 64 + lane]);
  }
  out[(long long)row * 64 + lane] = acc * (1.0f / 3.0f);
}

extern "C" void kernel_launch(void* const* d_in, const int* in_sizes, int n_in,
                              void* d_out, int out_size, void* d_ws, size_t ws_size,
                              hipStream_t stream) {
  const float* X0 = (const float*)d_in[0];
  const int* E1 = (const int*)d_in[1];
  const int* T2 = (const int*)d_in[2];
  const int* L0i = (const int*)d_in[3];
  const int* L1ai = (const int*)d_in[4];
  const int* L1bi = (const int*)d_in[5];
  const int* L2i = (const int*)d_in[6];
  const int* B1i = (const int*)d_in[7];
  const int* B2i = (const int*)d_in[9];
  const float* W = (const float*)d_in[11];
  const float* bvec = (const float*)d_in[12];
  // a1_w/a1_b are mathematically dead: s1[r] cancels in the row softmax.
  const float* a2w = (const float*)d_in[15];
  const float* a2b = (const float*)d_in[16];
  const float* pw = (const float*)d_in[17];
  const float* triW = (const float*)d_in[18];
  const float* trib = (const float*)d_in[19];
  float* out = (float*)d_out;

  char* base = (char*)d_ws;
  size_t off = 0;
  auto alloc = [&](size_t bytes) -> void* {
    void* p = base + off;
    off += (bytes + 255) & ~(size_t)255;
    return p;
  };
  unsigned short* Xb = (unsigned short*)alloc((size_t)N0 * KP * 2);
  unsigned short* Bp = (unsigned short*)alloc((size_t)3 * 65536 * 2);
  float* h0 = (float*)alloc((size_t)N0 * 64 * 4);
  float* h1 = (float*)alloc((size_t)N0 * 64 * 4);
  float* h2 = (float*)alloc((size_t)N1 * 64 * 4);
  float* h3 = (float*)alloc((size_t)N1 * 64 * 4);
  float* h4 = (float*)alloc((size_t)N2 * 64 * 4);   // h4+h5 contiguous: reused as Tm (N1 x 64)
  float* h5 = (float*)alloc((size_t)N2 * 64 * 4);
  float* Tm = h4;
  float* s2_0 = (float*)alloc((size_t)N0 * 4);
  float* s2_1 = (float*)alloc((size_t)N0 * 4);
  float* s2_2 = (float*)alloc((size_t)N1 * 4);
  float* s2_3 = (float*)alloc((size_t)N1 * 4);
  float* s2_4 = (float*)alloc((size_t)N2 * 4);
  float* s2_5 = (float*)alloc((size_t)N2 * 4);
  float* H0 = (float*)alloc((size_t)N0 * 64 * 4);
  float* H1 = (float*)alloc((size_t)N1 * 64 * 4);
  float* H2 = (float*)alloc((size_t)N2 * 64 * 4);
  int* gscan = (int*)alloc((size_t)(CNT_TOT + 1) * 4);  // all six rowptr arrays as slices
  int* pool = (int*)alloc((size_t)POOL_TOT * 4);        // all six col/entry arrays, absolute idx
  int* bsum = (int*)alloc((size_t)(SCAN_BLOCKS + 1) * 4);
  int* cnt = (int*)alloc((size_t)CNT_TOT * 4);
  int* cur = (int*)alloc((size_t)CNT_TOT * 4);

  hipMemsetAsync(cnt, 0, (size_t)CNT_TOT * 4, stream);
  hipMemsetAsync(cur, 0, (size_t)CNT_TOT * 4, stream);

  pack_x_kernel<<<(N0 * KP + 255) / 256, 256, 0, stream>>>(X0, Xb);
  pack_w_kernel<<<(3 * 65536 + 255) / 256, 256, 0, stream>>>(W, Bp);

  gemm_sat_kernel<1><<<(N0 + 63) / 64, 256, 0, stream>>>(Xb, nullptr, Bp, bvec, a2w, a2b, 0, N0, h0, h1, s2_0, s2_1);
  gemm_sat_kernel<2><<<(N1 + 63) / 64, 256, 0, stream>>>(Xb, E1, Bp + 65536, bvec, a2w, a2b, 2, N1, h2, h3, s2_2, s2_3);
  gemm_sat_kernel<3><<<(N2 + 63) / 64, 256, 0, stream>>>(Xb, T2, Bp + 2 * 65536, bvec, a2w, a2b, 4, N2, h4, h5, s2_4, s2_5);

  // histograms into the concatenated count array
  count_rows_kernel<<<(NNZ0 + 255) / 256, 256, 0, stream>>>(L0i, cnt + SEG_L0, NNZ0);
  count_rows_kernel<<<(NNZ1 + 255) / 256, 256, 0, stream>>>(L1ai, cnt + SEG_L1A, NNZ1);
  count_rows_kernel<<<(NNZ1 + 255) / 256, 256, 0, stream>>>(L1bi, cnt + SEG_L1B, NNZ1);
  count_rows_kernel<<<(NNZ2 + 255) / 256, 256, 0, stream>>>(L2i, cnt + SEG_L2, NNZ2);
  count_rows_kernel<<<(2 * N1 + 255) / 256, 256, 0, stream>>>(B1i, cnt + SEG_B1, 2 * N1);
  count_rows_kernel<<<(3 * N2 + 255) / 256, 256, 0, stream>>>(B2i, cnt + SEG_B2, 3 * N2);

  // one global scan serves all six CSRs
  scan_partial_kernel<<<SCAN_BLOCKS, 256, 0, stream>>>(cnt, bsum);
  scan_bsum_kernel<<<1, 256, 0, stream>>>(bsum, SCAN_BLOCKS);
  scan_write_kernel<<<SCAN_BLOCKS, 256, 0, stream>>>(cnt, bsum, gscan);

  const int* rp0 = gscan + SEG_L0;
  const int* rp1a = gscan + SEG_L1A;
  const int* rp1b = gscan + SEG_L1B;
  const int* rp2 = gscan + SEG_L2;
  const int* rpB1 = gscan + SEG_B1;
  const int* rpB2 = gscan + SEG_B2;

  fill_csr_kernel<<<(NNZ0 + 255) / 256, 256, 0, stream>>>(L0i, L0i + NNZ0, rp0, cur + SEG_L0, pool, NNZ0);
  fill_csr_kernel<<<(NNZ1 + 255) / 256, 256, 0, stream>>>(L1ai, L1ai + NNZ1, rp1a, cur + SEG_L1A, pool, NNZ1);
  fill_csr_kernel<<<(NNZ1 + 255) / 256, 256, 0, stream>>>(L1bi, L1bi + NNZ1, rp1b, cur + SEG_L1B, pool, NNZ1);
  fill_csr_kernel<<<(NNZ2 + 255) / 256, 256, 0, stream>>>(L2i, L2i + NNZ2, rp2, cur + SEG_L2, pool, NNZ2);
  fill_csr_kernel<<<(2 * N1 + 255) / 256, 256, 0, stream>>>(B1i, nullptr, rpB1, cur + SEG_B1, pool, 2 * N1);
  fill_csr_kernel<<<(3 * N2 + 255) / 256, 256, 0, stream>>>(B2i, nullptr, rpB2, cur + SEG_B2, pool, 3 * N2);

  sat_dual_kernel<<<(N0 + 3) / 4, 256, 0, stream>>>(rp0, pool, s2_0, h0, s2_1, h1, pw, H0, N0);
  sat_single_kernel<false><<<(N1 + 3) / 4, 256, 0, stream>>>(rp1a, pool, s2_2, h2, H1, N1);
  sat_single_kernel<true><<<(N1 + 3) / 4, 256, 0, stream>>>(rp1b, pool, s2_3, h3, H1, N1);
  prelu_kernel<<<(N1 * 64 + 255) / 256, 256, 0, stream>>>(H1, pw, N1 * 64);
  sat_dual_kernel<<<(N2 + 3) / 4, 256, 0, stream>>>(rp2, pool, s2_4, h4, s2_5, h5, pw, H2, N2);

  spmm_b2_kernel<<<(N1 + 3) / 4, 256, 0, stream>>>(rpB2, pool, H2, Tm, N1);   // h4/h5 dead now
  tri_gemm_kernel<<<(N1 + 3) / 4, 256, 0, stream>>>(Tm, triW, trib, N1);
  final_kernel<<<(N0 + 3) / 4, 256, 0, stream>>>(rpB1, pool, H0, H1, Tm, out, N0);
}

// Round 3
// 1424.733 us; speedup vs baseline: 2.3641x; 1.4872x over previous
//
#include <hip/hip_runtime.h>
#include <hip/hip_fp16.h>

static constexpr int N0 = 50000;
static constexpr int N1 = 200000;
static constexpr int N2 = 100000;
static constexpr int NNZ0 = 600000;
static constexpr int NNZ1 = 1000000;
static constexpr int NNZ2 = 600000;
static constexpr int FIN = 500;

// concatenated count layout: [L0 | L1a | L1b | L2 | B1 | B2]
static constexpr int SEG_L0 = 0;
static constexpr int SEG_L1A = 50000;
static constexpr int SEG_L1B = 250000;
static constexpr int SEG_L2 = 450000;
static constexpr int SEG_B1 = 550000;
static constexpr int SEG_B2 = 600000;
static constexpr int CNT_TOT = 800000;
static constexpr int POOL_TOT = NNZ0 + NNZ1 + NNZ1 + NNZ2 + 2 * N1 + 3 * N2;  // 3.9M
static constexpr int SCAN_CHUNK = 4096;
static constexpr int SCAN_BLOCKS = (CNT_TOT + SCAN_CHUNK - 1) / SCAN_CHUNK;    // 196

typedef __attribute__((ext_vector_type(8))) short bf16x8;
typedef __attribute__((ext_vector_type(8))) _Float16 f16x8;
typedef __attribute__((ext_vector_type(4))) float f32x4;

__device__ __forceinline__ unsigned short f2bf(float f) {
  unsigned int b = __float_as_uint(f);
  b = (b + 0x7FFFu + ((b >> 16) & 1u)) >> 16;   // RNE
  return (unsigned short)b;
}

// ---------- pack X0 -> binary bitmasks: 512 bits = 16 uints per row (3.2 MB, L2-resident) ----------
__global__ __launch_bounds__(256) void pack_bits_kernel(const float* __restrict__ X0,
                                                        unsigned int* __restrict__ Xbit) {
  int row = blockIdx.x * 4 + (threadIdx.x >> 6);
  if (row >= N0) return;
  int lane = threadIdx.x & 63;
  const float* xr = X0 + (long long)row * FIN;
#pragma unroll
  for (int i = 0; i < 8; ++i) {
    int c = i * 64 + lane;
    bool pred = (c < FIN) && (xr[c] != 0.0f);
    unsigned long long m = __ballot(pred);     // bit l = col i*64+l
    if (lane == 0) {
      Xbit[row * 16 + 2 * i] = (unsigned int)m;
      Xbit[row * 16 + 2 * i + 1] = (unsigned int)(m >> 32);
    }
  }
}

// ---------- pack W -> bf16 MFMA B-fragment layout: [level][kc][nb][lane][j] ----------
__global__ void pack_w_kernel(const float* __restrict__ W, unsigned short* __restrict__ Bp) {
  int g = blockIdx.x * 256 + threadIdx.x;
  if (g >= 3 * 65536) return;
  int j = g & 7;
  int lane = (g >> 3) & 63;
  int nb = (g >> 9) & 7;
  int kc = (g >> 12) & 15;
  int level = g >> 16;
  int k = kc * 32 + (lane >> 4) * 8 + j;
  int col128 = nb * 16 + (lane & 15);
  int head = level * 2 + (col128 >> 6);
  int col = col128 & 63;
  float f = 0.0f;
  if (k < FIN) f = W[((long long)head * FIN + k) * 64 + col];
  Bp[g] = f2bf(f);
}

// ---------- pack triW -> f16 B-fragment layout: [kc(2)][nb(4)][lane][j] ----------
__global__ void pack_wt_kernel(const float* __restrict__ triW, __half* __restrict__ Wt) {
  int g = blockIdx.x * 256 + threadIdx.x;
  if (g >= 4096) return;
  int j = g & 7;
  int lane = (g >> 3) & 63;
  int nb = (g >> 9) & 3;
  int kc = g >> 11;
  int k = kc * 32 + (lane >> 4) * 8 + j;
  int col = nb * 16 + (lane & 15);
  Wt[g] = __float2half(triW[k * 64 + col]);
}

// ---------- fused bit-gather(AND) + in-register bf16 expansion + MFMA + s2 epilogue ----------
// Tile: 64 rows x 128 cols (two heads), K=512. 4 waves; wave w -> rows 16w..16w+15.
template <int NSRC>
__global__ __launch_bounds__(256) void gemm_sat_kernel(
    const unsigned int* __restrict__ Xbit, const int* __restrict__ srcidx,
    const unsigned short* __restrict__ Bp, const float* __restrict__ bvec,
    const float* __restrict__ a2w, const float* __restrict__ a2b, int head_lo,
    int M, __half* __restrict__ h_lo, __half* __restrict__ h_hi,
    float* __restrict__ s2_lo, float* __restrict__ s2_hi) {
  __shared__ __align__(16) unsigned int Sb[64 * 20];   // row stride 20 uints (80 B) vs bank-32
  const int tid = threadIdx.x;
  const int m0 = blockIdx.x * 64;
  {
    int r = tid >> 2, c = tid & 3;
    int rg = m0 + r;
    uint4 a = make_uint4(0u, 0u, 0u, 0u);
    if (rg < M) {
      if (NSRC == 1) {
        a = *(const uint4*)(Xbit + (long long)rg * 16 + c * 4);
      } else if (NSRC == 2) {
        uint4 u = *(const uint4*)(Xbit + (long long)srcidx[2 * rg + 0] * 16 + c * 4);
        uint4 v = *(const uint4*)(Xbit + (long long)srcidx[2 * rg + 1] * 16 + c * 4);
        a.x = u.x & v.x; a.y = u.y & v.y; a.z = u.z & v.z; a.w = u.w & v.w;
      } else {
        uint4 u = *(const uint4*)(Xbit + (long long)srcidx[3 * rg + 0] * 16 + c * 4);
        uint4 v = *(const uint4*)(Xbit + (long long)srcidx[3 * rg + 1] * 16 + c * 4);
        uint4 w = *(const uint4*)(Xbit + (long long)srcidx[3 * rg + 2] * 16 + c * 4);
        a.x = u.x & v.x & w.x; a.y = u.y & v.y & w.y; a.z = u.z & v.z & w.z; a.w = u.w & v.w & w.w;
      }
    }
    *(uint4*)(Sb + r * 20 + c * 4) = a;
  }
  __syncthreads();

  const int wave = tid >> 6;
  const int lane = tid & 63;
  const int quad = lane >> 4;
  const int l16 = lane & 15;
  unsigned int bits[16];
  {
    const uint4* sp = (const uint4*)(Sb + (wave * 16 + l16) * 20);
#pragma unroll
    for (int c = 0; c < 4; ++c) *(uint4*)(bits + c * 4) = sp[c];
  }
  f32x4 acc[8];
#pragma unroll
  for (int i = 0; i < 8; ++i) acc[i] = (f32x4){0.f, 0.f, 0.f, 0.f};
  const bf16x8* Bf = (const bf16x8*)Bp;
#pragma unroll 4
  for (int kc = 0; kc < 16; ++kc) {
    // A[m=l16][k=kc*32+quad*8+j] <- bit (quad*8+j) of bits[kc]; expand 2 bits/word
    unsigned int byte = (bits[kc] >> (quad * 8)) & 0xFFu;
    bf16x8 af;
#pragma unroll
    for (int j = 0; j < 4; ++j) {
      unsigned int b2 = (byte >> (2 * j)) & 3u;
      ((unsigned int*)&af)[j] = ((b2 & 1u) | ((b2 & 2u) << 15)) * 0x3F80u;
    }
#pragma unroll
    for (int nb = 0; nb < 8; ++nb) {
      bf16x8 bf = Bf[(kc * 8 + nb) * 64 + lane];
      acc[nb] = __builtin_amdgcn_mfma_f32_16x16x32_bf16(af, bf, acc[nb], 0, 0, 0);
    }
  }

  // epilogue: bias, store h (fp16), s2 = h . a2w + a2b via 16-lane reduce
  float plo[4] = {0.f, 0.f, 0.f, 0.f};
  float phi[4] = {0.f, 0.f, 0.f, 0.f};
#pragma unroll
  for (int nb = 0; nb < 8; ++nb) {
    int col128 = nb * 16 + l16;
    int hh = col128 >> 6;
    int col = col128 & 63;
    float bia = bvec[(head_lo + hh) * 64 + col];
    float aw = a2w[(head_lo + hh) * 64 + col];
    __half* hdst = hh ? h_hi : h_lo;
#pragma unroll
    for (int reg = 0; reg < 4; ++reg) {
      int rg = m0 + wave * 16 + quad * 4 + reg;     // C/D: row=quad*4+reg, col=l16
      float v = acc[nb][reg] + bia;
      if (rg < M) hdst[(long long)rg * 64 + col] = __float2half(v);
      if (hh) phi[reg] += v * aw; else plo[reg] += v * aw;
    }
  }
#pragma unroll
  for (int off = 1; off < 16; off <<= 1) {
#pragma unroll
    for (int reg = 0; reg < 4; ++reg) {
      plo[reg] += __shfl_xor(plo[reg], off);
      phi[reg] += __shfl_xor(phi[reg], off);
    }
  }
  if (l16 == 0) {
    float blo = a2b[head_lo];
    float bhi = a2b[head_lo + 1];
#pragma unroll
    for (int reg = 0; reg < 4; ++reg) {
      int rg = m0 + wave * 16 + quad * 4 + reg;
      if (rg < M) { s2_lo[rg] = plo[reg] + blo; s2_hi[rg] = phi[reg] + bhi; }
    }
  }
}

// ---------- CSR build ----------
__global__ void count_rows_kernel(const int* __restrict__ rows, int* __restrict__ cnt, int nnz) {
  int g = blockIdx.x * 256 + threadIdx.x;
  if (g < nnz) atomicAdd(&cnt[rows[g]], 1);
}

__global__ __launch_bounds__(256) void scan_partial_kernel(const int* __restrict__ cnt,
                                                           int* __restrict__ bsum) {
  __shared__ int s[256];
  int b = blockIdx.x, t = threadIdx.x;
  int base = b * SCAN_CHUNK + t * 16;
  int sum = 0;
#pragma unroll
  for (int i = 0; i < 16; ++i) {
    int idx = base + i;
    if (idx < CNT_TOT) sum += cnt[idx];
  }
  s[t] = sum;
  __syncthreads();
  for (int off = 128; off > 0; off >>= 1) {
    if (t < off) s[t] += s[t + off];
    __syncthreads();
  }
  if (t == 0) bsum[b] = s[0];
}

__global__ __launch_bounds__(256) void scan_bsum_kernel(int* __restrict__ bsum, int nb) {
  __shared__ int s[256];
  int t = threadIdx.x;
  int v = (t < nb) ? bsum[t] : 0;
  s[t] = v;
  __syncthreads();
  for (int off = 1; off < 256; off <<= 1) {
    int u = (t >= off) ? s[t - off] : 0;
    __syncthreads();
    s[t] += u;
    __syncthreads();
  }
  if (t < nb) bsum[t] = (t == 0) ? 0 : s[t - 1];
  if (t == 0) bsum[nb] = s[nb - 1];
}

__global__ __launch_bounds__(256) void scan_write_kernel(const int* __restrict__ cnt,
                                                         const int* __restrict__ bsum,
                                                         int* __restrict__ gscan) {
  __shared__ int s[256];
  int b = blockIdx.x, t = threadIdx.x;
  int base = b * SCAN_CHUNK + t * 16;
  int loc[16];
  int sum = 0;
#pragma unroll
  for (int i = 0; i < 16; ++i) {
    int idx = base + i;
    int v = (idx < CNT_TOT) ? cnt[idx] : 0;
    loc[i] = sum;
    sum += v;
  }
  s[t] = sum;
  __syncthreads();
  for (int off = 1; off < 256; off <<= 1) {
    int u = (t >= off) ? s[t - off] : 0;
    __syncthreads();
    s[t] += u;
    __syncthreads();
  }
  int toff = bsum[b] + ((t == 0) ? 0 : s[t - 1]);
#pragma unroll
  for (int i = 0; i < 16; ++i) {
    int idx = base + i;
    if (idx < CNT_TOT) gscan[idx] = toff + loc[i];
  }
  if (b == 0 && t == 0) gscan[CNT_TOT] = bsum[SCAN_BLOCKS];
}

__global__ void fill_csr_kernel(const int* __restrict__ rows, const int* __restrict__ cols,
                                const int* __restrict__ rowptr, int* __restrict__ cur,
                                int* __restrict__ pool, int nnz) {
  int g = blockIdx.x * 256 + threadIdx.x;
  if (g >= nnz) return;
  int r = rows[g];
  int pos = rowptr[r] + atomicAdd(&cur[r], 1);
  pool[pos] = cols ? cols[g] : g;
}

// ---------- SAT kernels: wave per row, lane = dim; h tables fp16 ----------
template <typename OutT>
__global__ __launch_bounds__(256) void sat_dual_kernel(
    const int* __restrict__ rowptr, const int* __restrict__ col,
    const float* __restrict__ s2a, const __half* __restrict__ ha,
    const float* __restrict__ s2b, const __half* __restrict__ hb,
    const float* __restrict__ pw, OutT* __restrict__ out, int n) {
  int row = blockIdx.x * 4 + (threadIdx.x >> 6);
  if (row >= n) return;
  int lane = threadIdx.x & 63;
  int p0 = rowptr[row], p1 = rowptr[row + 1];
  float ma = -3.0e38f, mb = -3.0e38f;
  for (int p = p0 + lane; p < p1; p += 64) {
    int c = col[p];
    ma = fmaxf(ma, s2a[c]); mb = fmaxf(mb, s2b[c]);
  }
#pragma unroll
  for (int off = 32; off > 0; off >>= 1) {
    ma = fmaxf(ma, __shfl_xor(ma, off)); mb = fmaxf(mb, __shfl_xor(mb, off));
  }
  float za = 0.f, zb = 0.f;
  for (int p = p0 + lane; p < p1; p += 64) {
    int c = col[p];
    za += __expf(s2a[c] - ma); zb += __expf(s2b[c] - mb);
  }
#pragma unroll
  for (int off = 32; off > 0; off >>= 1) {
    za += __shfl_xor(za, off); zb += __shfl_xor(zb, off);
  }
  float ia = (p1 > p0) ? 1.f / za : 0.f;
  float ib = (p1 > p0) ? 1.f / zb : 0.f;
  float acc = 0.f;
  for (int p = p0; p < p1; ++p) {
    int c = col[p];
    float wa = __expf(s2a[c] - ma) * ia;
    float wb = __expf(s2b[c] - mb) * ib;
    acc += wa * __half2float(ha[(long long)c * 64 + lane]) +
           wb * __half2float(hb[(long long)c * 64 + lane]);
  }
  float pv = pw[0];
  float r = acc >= 0.f ? acc : pv * acc;   // prelu fused
  out[(long long)row * 64 + lane] = (OutT)r;
}

__global__ __launch_bounds__(256) void sat_single_kernel(
    const int* __restrict__ rowptr, const int* __restrict__ col,
    const float* __restrict__ s2, const __half* __restrict__ h,
    float* __restrict__ out, int n) {
  int row = blockIdx.x * 4 + (threadIdx.x >> 6);
  if (row >= n) return;
  int lane = threadIdx.x & 63;
  int p0 = rowptr[row], p1 = rowptr[row + 1];
  float m = -3.0e38f;
  for (int p = p0 + lane; p < p1; p += 64) m = fmaxf(m, s2[col[p]]);
#pragma unroll
  for (int off = 32; off > 0; off >>= 1) m = fmaxf(m, __shfl_xor(m, off));
  float z = 0.f;
  for (int p = p0 + lane; p < p1; p += 64) z += __expf(s2[col[p]] - m);
#pragma unroll
  for (int off = 32; off > 0; off >>= 1) z += __shfl_xor(z, off);
  float iz = (p1 > p0) ? 1.f / z : 0.f;
  float acc = 0.f;
  for (int p = p0; p < p1; ++p) {
    int c = col[p];
    acc += (__expf(s2[c] - m) * iz) * __half2float(h[(long long)c * 64 + lane]);
  }
  out[(long long)row * 64 + lane] = acc;
}

// second head: add to tmp, prelu, write fp16
__global__ __launch_bounds__(256) void sat_single_add_prelu_kernel(
    const int* __restrict__ rowptr, const int* __restrict__ col,
    const float* __restrict__ s2, const __half* __restrict__ h,
    const float* __restrict__ tmp, const float* __restrict__ pw,
    __half* __restrict__ out, int n) {
  int row = blockIdx.x * 4 + (threadIdx.x >> 6);
  if (row >= n) return;
  int lane = threadIdx.x & 63;
  int p0 = rowptr[row], p1 = rowptr[row + 1];
  float m = -3.0e38f;
  for (int p = p0 + lane; p < p1; p += 64) m = fmaxf(m, s2[col[p]]);
#pragma unroll
  for (int off = 32; off > 0; off >>= 1) m = fmaxf(m, __shfl_xor(m, off));
  float z = 0.f;
  for (int p = p0 + lane; p < p1; p += 64) z += __expf(s2[col[p]] - m);
#pragma unroll
  for (int off = 32; off > 0; off >>= 1) z += __shfl_xor(z, off);
  float iz = (p1 > p0) ? 1.f / z : 0.f;
  float acc = tmp[(long long)row * 64 + lane];
  for (int p = p0; p < p1; ++p) {
    int c = col[p];
    acc += (__expf(s2[c] - m) * iz) * __half2float(h[(long long)c * 64 + lane]);
  }
  float pv = pw[0];
  float r = acc >= 0.f ? acc : pv * acc;
  out[(long long)row * 64 + lane] = __float2half(r);
}

// ---------- Tm_pre = B2 @ H2 (fp16 out) ----------
__global__ __launch_bounds__(256) void spmm_b2_kernel(
    const int* __restrict__ rowptr, const int* __restrict__ ent,
    const __half* __restrict__ H2, __half* __restrict__ Tmp, int n) {
  int row = blockIdx.x * 4 + (threadIdx.x >> 6);
  if (row >= n) return;
  int lane = threadIdx.x & 63;
  int p0 = rowptr[row], p1 = rowptr[row + 1];
  float acc = 0.f;
  for (int p = p0; p < p1; ++p) {
    int e = ent[p];
    int c = e / 3;
    float s = (e - 3 * c == 1) ? -1.f : 1.f;
    acc += s * __half2float(H2[(long long)c * 64 + lane]);
  }
  Tmp[(long long)row * 64 + lane] = __float2half(acc);
}

// ---------- Tm = Tm_pre @ triW + trib via f16 MFMA (M=64-tile, K=64, N=64) ----------
__global__ __launch_bounds__(256) void tri_mfma_kernel(
    const __half* __restrict__ Tmp, const __half* __restrict__ Wt,
    const float* __restrict__ trib, __half* __restrict__ Tm, int n) {
  const int tid = threadIdx.x;
  const int m0 = blockIdx.x * 64;
  const int wave = tid >> 6;
  const int lane = tid & 63;
  const int quad = lane >> 4;
  const int l16 = lane & 15;
  const int arow = m0 + wave * 16 + l16;
  f32x4 acc[4];
#pragma unroll
  for (int i = 0; i < 4; ++i) acc[i] = (f32x4){0.f, 0.f, 0.f, 0.f};
  const f16x8* Wf = (const f16x8*)Wt;
#pragma unroll
  for (int kc = 0; kc < 2; ++kc) {
    f16x8 af = (f16x8){0, 0, 0, 0, 0, 0, 0, 0};
    if (arow < n) af = *(const f16x8*)((const _Float16*)Tmp + (long long)arow * 64 + kc * 32 + quad * 8);
#pragma unroll
    for (int nb = 0; nb < 4; ++nb) {
      f16x8 bf = Wf[(kc * 4 + nb) * 64 + lane];
      acc[nb] = __builtin_amdgcn_mfma_f32_16x16x32_f16(af, bf, acc[nb], 0, 0, 0);
    }
  }
#pragma unroll
  for (int nb = 0; nb < 4; ++nb) {
    int col = nb * 16 + l16;
    float bia = trib[col];
#pragma unroll
    for (int reg = 0; reg < 4; ++reg) {
      int rg = m0 + wave * 16 + quad * 4 + reg;
      if (rg < n) Tm[(long long)rg * 64 + col] = __float2half(acc[nb][reg] + bia);
    }
  }
}

// ---------- out = (H0 + B1 @ (H1 + Tm)) / 3 ----------
__global__ __launch_bounds__(256) void final_kernel(
    const int* __restrict__ rowptr, const int* __restrict__ ent,
    const float* __restrict__ H0, const __half* __restrict__ H1,
    const __half* __restrict__ Tm, float* __restrict__ out, int n) {
  int row = blockIdx.x * 4 + (threadIdx.x >> 6);
  if (row >= n) return;
  int lane = threadIdx.x & 63;
  int p0 = rowptr[row], p1 = rowptr[row + 1];
  float acc = H0[(long long)row * 64 + lane];
  for (int p = p0; p < p1; ++p) {
    int e = ent[p];
    int c = e >> 1;
    float s = (e & 1) ? -1.f : 1.f;
    acc += s * (__half2float(H1[(long long)c * 64 + lane]) +
                __half2float(Tm[(long long)c * 64 + lane]));
  }
  out[(long long)row * 64 + lane] = acc * (1.0f / 3.0f);
}

extern "C" void kernel_launch(void* const* d_in, const int* in_sizes, int n_in,
                              void* d_out, int out_size, void* d_ws, size_t ws_size,
                              hipStream_t stream) {
  const float* X0 = (const float*)d_in[0];
  const int* E1 = (const int*)d_in[1];
  const int* T2 = (const int*)d_in[2];
  const int* L0i = (const int*)d_in[3];
  const int* L1ai = (const int*)d_in[4];
  const int* L1bi = (const int*)d_in[5];
  const int* L2i = (const int*)d_in[6];
  const int* B1i = (const int*)d_in[7];
  const int* B2i = (const int*)d_in[9];
  const float* W = (const float*)d_in[11];
  const float* bvec = (const float*)d_in[12];
  // a1_w/a1_b are mathematically dead: s1[r] cancels in the row softmax.
  const float* a2w = (const float*)d_in[15];
  const float* a2b = (const float*)d_in[16];
  const float* pw = (const float*)d_in[17];
  const float* triW = (const float*)d_in[18];
  const float* trib = (const float*)d_in[19];
  float* out = (float*)d_out;

  char* base = (char*)d_ws;
  size_t off = 0;
  auto alloc = [&](size_t bytes) -> void* {
    void* p = base + off;
    off += (bytes + 255) & ~(size_t)255;
    return p;
  };
  unsigned int* Xbit = (unsigned int*)alloc((size_t)N0 * 16 * 4);        // 3.2 MB
  unsigned short* Bp = (unsigned short*)alloc((size_t)3 * 65536 * 2);
  __half* Wt = (__half*)alloc((size_t)4096 * 2);
  __half* h0 = (__half*)alloc((size_t)N0 * 64 * 2);
  __half* h1 = (__half*)alloc((size_t)N0 * 64 * 2);
  __half* h2 = (__half*)alloc((size_t)N1 * 64 * 2);
  __half* h3 = (__half*)alloc((size_t)N1 * 64 * 2);
  __half* h4 = (__half*)alloc((size_t)N2 * 64 * 2);
  __half* h5 = (__half*)alloc((size_t)N2 * 64 * 2);
  float* s2_0 = (float*)alloc((size_t)N0 * 4);
  float* s2_1 = (float*)alloc((size_t)N0 * 4);
  float* s2_2 = (float*)alloc((size_t)N1 * 4);
  float* s2_3 = (float*)alloc((size_t)N1 * 4);
  float* s2_4 = (float*)alloc((size_t)N2 * 4);
  float* s2_5 = (float*)alloc((size_t)N2 * 4);
  float* H0 = (float*)alloc((size_t)N0 * 64 * 4);
  float* H1tmp = (float*)alloc((size_t)N1 * 64 * 4);
  __half* H1 = (__half*)alloc((size_t)N1 * 64 * 2);
  __half* H2 = (__half*)alloc((size_t)N2 * 64 * 2);
  __half* Tmp = (__half*)alloc((size_t)N1 * 64 * 2);
  __half* Tm = (__half*)alloc((size_t)N1 * 64 * 2);
  int* gscan = (int*)alloc((size_t)(CNT_TOT + 1) * 4);
  int* pool = (int*)alloc((size_t)POOL_TOT * 4);
  int* bsum = (int*)alloc((size_t)(SCAN_BLOCKS + 1) * 4);
  int* cnt = (int*)alloc((size_t)CNT_TOT * 4);
  int* cur = (int*)alloc((size_t)CNT_TOT * 4);

  hipMemsetAsync(cnt, 0, (size_t)CNT_TOT * 4, stream);
  hipMemsetAsync(cur, 0, (size_t)CNT_TOT * 4, stream);

  pack_bits_kernel<<<(N0 + 3) / 4, 256, 0, stream>>>(X0, Xbit);
  pack_w_kernel<<<(3 * 65536 + 255) / 256, 256, 0, stream>>>(W, Bp);
  pack_wt_kernel<<<16, 256, 0, stream>>>(triW, Wt);

  gemm_sat_kernel<1><<<(N0 + 63) / 64, 256, 0, stream>>>(Xbit, nullptr, Bp, bvec, a2w, a2b, 0, N0, h0, h1, s2_0, s2_1);
  gemm_sat_kernel<2><<<(N1 + 63) / 64, 256, 0, stream>>>(Xbit, E1, Bp + 65536, bvec, a2w, a2b, 2, N1, h2, h3, s2_2, s2_3);
  gemm_sat_kernel<3><<<(N2 + 63) / 64, 256, 0, stream>>>(Xbit, T2, Bp + 2 * 65536, bvec, a2w, a2b, 4, N2, h4, h5, s2_4, s2_5);

  count_rows_kernel<<<(NNZ0 + 255) / 256, 256, 0, stream>>>(L0i, cnt + SEG_L0, NNZ0);
  count_rows_kernel<<<(NNZ1 + 255) / 256, 256, 0, stream>>>(L1ai, cnt + SEG_L1A, NNZ1);
  count_rows_kernel<<<(NNZ1 + 255) / 256, 256, 0, stream>>>(L1bi, cnt + SEG_L1B, NNZ1);
  count_rows_kernel<<<(NNZ2 + 255) / 256, 256, 0, stream>>>(L2i, cnt + SEG_L2, NNZ2);
  count_rows_kernel<<<(2 * N1 + 255) / 256, 256, 0, stream>>>(B1i, cnt + SEG_B1, 2 * N1);
  count_rows_kernel<<<(3 * N2 + 255) / 256, 256, 0, stream>>>(B2i, cnt + SEG_B2, 3 * N2);

  scan_partial_kernel<<<SCAN_BLOCKS, 256, 0, stream>>>(cnt, bsum);
  scan_bsum_kernel<<<1, 256, 0, stream>>>(bsum, SCAN_BLOCKS);
  scan_write_kernel<<<SCAN_BLOCKS, 256, 0, stream>>>(cnt, bsum, gscan);

  const int* rp0 = gscan + SEG_L0;
  const int* rp1a = gscan + SEG_L1A;
  const int* rp1b = gscan + SEG_L1B;
  const int* rp2 = gscan + SEG_L2;
  const int* rpB1 = gscan + SEG_B1;
  const int* rpB2 = gscan + SEG_B2;

  fill_csr_kernel<<<(NNZ0 + 255) / 256, 256, 0, stream>>>(L0i, L0i + NNZ0, rp0, cur + SEG_L0, pool, NNZ0);
  fill_csr_kernel<<<(NNZ1 + 255) / 256, 256, 0, stream>>>(L1ai, L1ai + NNZ1, rp1a, cur + SEG_L1A, pool, NNZ1);
  fill_csr_kernel<<<(NNZ1 + 255) / 256, 256, 0, stream>>>(L1bi, L1bi + NNZ1, rp1b, cur + SEG_L1B, pool, NNZ1);
  fill_csr_kernel<<<(NNZ2 + 255) / 256, 256, 0, stream>>>(L2i, L2i + NNZ2, rp2, cur + SEG_L2, pool, NNZ2);
  fill_csr_kernel<<<(2 * N1 + 255) / 256, 256, 0, stream>>>(B1i, nullptr, rpB1, cur + SEG_B1, pool, 2 * N1);
  fill_csr_kernel<<<(3 * N2 + 255) / 256, 256, 0, stream>>>(B2i, nullptr, rpB2, cur + SEG_B2, pool, 3 * N2);

  sat_dual_kernel<float><<<(N0 + 3) / 4, 256, 0, stream>>>(rp0, pool, s2_0, h0, s2_1, h1, pw, H0, N0);
  sat_single_kernel<<<(N1 + 3) / 4, 256, 0, stream>>>(rp1a, pool, s2_2, h2, H1tmp, N1);
  sat_single_add_prelu_kernel<<<(N1 + 3) / 4, 256, 0, stream>>>(rp1b, pool, s2_3, h3, H1tmp, pw, H1, N1);
  sat_dual_kernel<__half><<<(N2 + 3) / 4, 256, 0, stream>>>(rp2, pool, s2_4, h4, s2_5, h5, pw, H2, N2);

  spmm_b2_kernel<<<(N1 + 3) / 4, 256, 0, stream>>>(rpB2, pool, H2, Tmp, N1);
  tri_mfma_kernel<<<(N1 + 63) / 64, 256, 0, stream>>>(Tmp, Wt, trib, Tm, N1);
  final_kernel<<<(N0 + 3) / 4, 256, 0, stream>>>(rpB1, pool, H0, H1, Tm, out, N0);
}

// Round 4
// 1131.156 us; speedup vs baseline: 2.9777x; 1.2595x over previous
//
#include <hip/hip_runtime.h>
#include <hip/hip_fp16.h>

static constexpr int N0 = 50000;
static constexpr int N1 = 200000;
static constexpr int N2 = 100000;
static constexpr int NNZ0 = 600000;
static constexpr int NNZ1 = 1000000;
static constexpr int NNZ2 = 600000;
static constexpr int FIN = 500;

// concatenated count layout: [L0 | L1a | L1b | L2 | B1 | B2]
static constexpr int SEG_L0 = 0;
static constexpr int SEG_L1A = 50000;
static constexpr int SEG_L1B = 250000;
static constexpr int SEG_L2 = 450000;
static constexpr int SEG_B1 = 550000;
static constexpr int SEG_B2 = 600000;
static constexpr int CNT_TOT = 800000;
static constexpr int TOT_E = NNZ0 + NNZ1 + NNZ1 + NNZ2 + 2 * N1 + 3 * N2;  // 3.9M
static constexpr int SCAN_CHUNK = 4096;
static constexpr int SCAN_BLOCKS = (CNT_TOT + SCAN_CHUNK - 1) / SCAN_CHUNK;  // 196

typedef __attribute__((ext_vector_type(8))) short bf16x8;
typedef __attribute__((ext_vector_type(8))) _Float16 f16x8;
typedef __attribute__((ext_vector_type(4))) float f32x4;

__device__ __forceinline__ unsigned short f2bf(float f) {
  unsigned int b = __float_as_uint(f);
  b = (b + 0x7FFFu + ((b >> 16) & 1u)) >> 16;   // RNE
  return (unsigned short)b;
}

// ---------- pack X0 -> binary bitmasks: 512 bits = 16 uints per row (3.2 MB, L2-resident) ----------
__global__ __launch_bounds__(256) void pack_bits_kernel(const float* __restrict__ X0,
                                                        unsigned int* __restrict__ Xbit) {
  int row = blockIdx.x * 4 + (threadIdx.x >> 6);
  if (row >= N0) return;
  int lane = threadIdx.x & 63;
  const float* xr = X0 + (long long)row * FIN;
#pragma unroll
  for (int i = 0; i < 8; ++i) {
    int c = i * 64 + lane;
    bool pred = (c < FIN) && (xr[c] != 0.0f);
    unsigned long long m = __ballot(pred);
    if (lane == 0) {
      Xbit[row * 16 + 2 * i] = (unsigned int)m;
      Xbit[row * 16 + 2 * i + 1] = (unsigned int)(m >> 32);
    }
  }
}

// ---------- pack W -> bf16 MFMA B-fragment layout: [level][kc][nb][lane][j] ----------
__global__ void pack_w_kernel(const float* __restrict__ W, unsigned short* __restrict__ Bp) {
  int g = blockIdx.x * 256 + threadIdx.x;
  if (g >= 3 * 65536) return;
  int j = g & 7;
  int lane = (g >> 3) & 63;
  int nb = (g >> 9) & 7;
  int kc = (g >> 12) & 15;
  int level = g >> 16;
  int k = kc * 32 + (lane >> 4) * 8 + j;
  int col128 = nb * 16 + (lane & 15);
  int head = level * 2 + (col128 >> 6);
  int col = col128 & 63;
  float f = 0.0f;
  if (k < FIN) f = W[((long long)head * FIN + k) * 64 + col];
  Bp[g] = f2bf(f);
}

// ---------- pack triW -> f16 B-fragment layout: [kc(2)][nb(4)][lane][j] ----------
__global__ void pack_wt_kernel(const float* __restrict__ triW, __half* __restrict__ Wt) {
  int g = blockIdx.x * 256 + threadIdx.x;
  if (g >= 4096) return;
  int j = g & 7;
  int lane = (g >> 3) & 63;
  int nb = (g >> 9) & 3;
  int kc = g >> 11;
  int k = kc * 32 + (lane >> 4) * 8 + j;
  int col = nb * 16 + (lane & 15);
  Wt[g] = __float2half(triW[k * 64 + col]);
}

// ---------- fused bit-gather(AND) + in-register bf16 expansion + MFMA ----------
// M-tile 256, 4 waves; wave w handles 4 subtiles of 16 rows (B fragments reused 4x).
// Epilogue stores h (fp16) and expv = exp(h . a2w + a2b) per head.
template <int NSRC>
__global__ __launch_bounds__(256) void gemm_sat_kernel(
    const unsigned int* __restrict__ Xbit, const int* __restrict__ srcidx,
    const unsigned short* __restrict__ Bp, const float* __restrict__ bvec,
    const float* __restrict__ a2w, const float* __restrict__ a2b, int head_lo,
    int M, __half* __restrict__ h_lo, __half* __restrict__ h_hi,
    float* __restrict__ e_lo, float* __restrict__ e_hi) {
  __shared__ __align__(16) unsigned int Sb[256 * 20];   // stride 20 uints: 2-way bank alias (free)
  const int tid = threadIdx.x;
  const int m0 = blockIdx.x * 256;
  {
    int rg = m0 + tid;
    uint4 a[4];
#pragma unroll
    for (int c = 0; c < 4; ++c) a[c] = make_uint4(0u, 0u, 0u, 0u);
    if (rg < M) {
      if (NSRC == 1) {
        const uint4* up = (const uint4*)(Xbit + (long long)rg * 16);
#pragma unroll
        for (int c = 0; c < 4; ++c) a[c] = up[c];
      } else if (NSRC == 2) {
        const uint4* up = (const uint4*)(Xbit + (long long)srcidx[2 * rg + 0] * 16);
        const uint4* vp = (const uint4*)(Xbit + (long long)srcidx[2 * rg + 1] * 16);
#pragma unroll
        for (int c = 0; c < 4; ++c) {
          uint4 u = up[c], v = vp[c];
          a[c] = make_uint4(u.x & v.x, u.y & v.y, u.z & v.z, u.w & v.w);
        }
      } else {
        const uint4* up = (const uint4*)(Xbit + (long long)srcidx[3 * rg + 0] * 16);
        const uint4* vp = (const uint4*)(Xbit + (long long)srcidx[3 * rg + 1] * 16);
        const uint4* wp = (const uint4*)(Xbit + (long long)srcidx[3 * rg + 2] * 16);
#pragma unroll
        for (int c = 0; c < 4; ++c) {
          uint4 u = up[c], v = vp[c], w = wp[c];
          a[c] = make_uint4(u.x & v.x & w.x, u.y & v.y & w.y, u.z & v.z & w.z, u.w & v.w & w.w);
        }
      }
    }
#pragma unroll
    for (int c = 0; c < 4; ++c) *(uint4*)(Sb + tid * 20 + c * 4) = a[c];
  }
  __syncthreads();

  const int wave = tid >> 6;
  const int lane = tid & 63;
  const int quad = lane >> 4;
  const int l16 = lane & 15;
  f32x4 acc[8][4];   // [nb][sub]
#pragma unroll
  for (int i = 0; i < 8; ++i)
#pragma unroll
    for (int s = 0; s < 4; ++s) acc[i][s] = (f32x4){0.f, 0.f, 0.f, 0.f};
  const bf16x8* Bf = (const bf16x8*)Bp;
#pragma unroll 2
  for (int kc = 0; kc < 16; ++kc) {
    bf16x8 af[4];
#pragma unroll
    for (int sub = 0; sub < 4; ++sub) {
      unsigned int bw = Sb[(wave * 64 + sub * 16 + l16) * 20 + kc];
      unsigned int byte = (bw >> (quad * 8)) & 0xFFu;
#pragma unroll
      for (int j = 0; j < 4; ++j) {
        unsigned int b2 = (byte >> (2 * j)) & 3u;
        ((unsigned int*)&af[sub])[j] = ((b2 & 1u) | ((b2 & 2u) << 15)) * 0x3F80u;
      }
    }
#pragma unroll
    for (int nb = 0; nb < 8; ++nb) {
      bf16x8 bf = Bf[(kc * 8 + nb) * 64 + lane];
#pragma unroll
      for (int sub = 0; sub < 4; ++sub)
        acc[nb][sub] = __builtin_amdgcn_mfma_f32_16x16x32_bf16(af[sub], bf, acc[nb][sub], 0, 0, 0);
    }
  }

  float bia[8], aw[8];
#pragma unroll
  for (int nb = 0; nb < 8; ++nb) {
    int col128 = nb * 16 + l16;
    int hh = col128 >> 6, col = col128 & 63;
    bia[nb] = bvec[(head_lo + hh) * 64 + col];
    aw[nb] = a2w[(head_lo + hh) * 64 + col];
  }
  float blo = a2b[head_lo], bhi = a2b[head_lo + 1];
#pragma unroll
  for (int sub = 0; sub < 4; ++sub) {
    float plo[4] = {0.f, 0.f, 0.f, 0.f};
    float phi[4] = {0.f, 0.f, 0.f, 0.f};
#pragma unroll
    for (int nb = 0; nb < 8; ++nb) {
      int col128 = nb * 16 + l16;
      int hh = col128 >> 6, col = col128 & 63;
      __half* hdst = hh ? h_hi : h_lo;
#pragma unroll
      for (int reg = 0; reg < 4; ++reg) {
        int rg = m0 + wave * 64 + sub * 16 + quad * 4 + reg;   // C/D: row=quad*4+reg, col=l16
        float v = acc[nb][sub][reg] + bia[nb];
        if (rg < M) hdst[(long long)rg * 64 + col] = __float2half(v);
        if (hh) phi[reg] += v * aw[nb]; else plo[reg] += v * aw[nb];
      }
    }
#pragma unroll
    for (int off = 1; off < 16; off <<= 1) {
#pragma unroll
      for (int reg = 0; reg < 4; ++reg) {
        plo[reg] += __shfl_xor(plo[reg], off);
        phi[reg] += __shfl_xor(phi[reg], off);
      }
    }
    if (l16 == 0) {
#pragma unroll
      for (int reg = 0; reg < 4; ++reg) {
        int rg = m0 + wave * 64 + sub * 16 + quad * 4 + reg;
        if (rg < M) {
          e_lo[rg] = __expf(plo[reg] + blo);   // |s2| <= ~4 by construction: no max needed
          e_hi[rg] = __expf(phi[reg] + bhi);
        }
      }
    }
  }
}

// ---------- merged CSR build: one histogram kernel + one fill kernel over all 6 segments ----------
__global__ __launch_bounds__(256) void count_all_kernel(
    const int* __restrict__ r0, const int* __restrict__ r1a, const int* __restrict__ r1b,
    const int* __restrict__ r2, const int* __restrict__ rb1, const int* __restrict__ rb2,
    int* __restrict__ cnt) {
  int g = blockIdx.x * 256 + threadIdx.x;
  if (g >= TOT_E) return;
  int seg, r;
  if (g < 600000) { seg = SEG_L0; r = r0[g]; }
  else if (g < 1600000) { seg = SEG_L1A; r = r1a[g - 600000]; }
  else if (g < 2600000) { seg = SEG_L1B; r = r1b[g - 1600000]; }
  else if (g < 3200000) { seg = SEG_L2; r = r2[g - 2600000]; }
  else if (g < 3600000) { seg = SEG_B1; r = rb1[g - 3200000]; }
  else { seg = SEG_B2; r = rb2[g - 3600000]; }
  atomicAdd(&cnt[seg + r], 1);
}

__global__ __launch_bounds__(256) void fill_all_kernel(
    const int* __restrict__ r0, const int* __restrict__ r1a, const int* __restrict__ r1b,
    const int* __restrict__ r2, const int* __restrict__ rb1, const int* __restrict__ rb2,
    const int* __restrict__ gscan, int* __restrict__ cur, int* __restrict__ pool) {
  int g = blockIdx.x * 256 + threadIdx.x;
  if (g >= TOT_E) return;
  int seg, r, val;
  if (g < 600000) { int l = g; seg = SEG_L0; r = r0[l]; val = r0[NNZ0 + l]; }
  else if (g < 1600000) { int l = g - 600000; seg = SEG_L1A; r = r1a[l]; val = r1a[NNZ1 + l]; }
  else if (g < 2600000) { int l = g - 1600000; seg = SEG_L1B; r = r1b[l]; val = r1b[NNZ1 + l]; }
  else if (g < 3200000) { int l = g - 2600000; seg = SEG_L2; r = r2[l]; val = r2[NNZ2 + l]; }
  else if (g < 3600000) { int l = g - 3200000; seg = SEG_B1; r = rb1[l]; val = l; }   // entry id
  else { int l = g - 3600000; seg = SEG_B2; r = rb2[l]; val = l; }
  int pos = gscan[seg + r] + atomicAdd(&cur[seg + r], 1);
  pool[pos] = val;
}

__global__ __launch_bounds__(256) void scan_partial_kernel(const int* __restrict__ cnt,
                                                           int* __restrict__ bsum) {
  __shared__ int s[256];
  int b = blockIdx.x, t = threadIdx.x;
  int base = b * SCAN_CHUNK + t * 16;
  int sum = 0;
#pragma unroll
  for (int i = 0; i < 16; ++i) {
    int idx = base + i;
    if (idx < CNT_TOT) sum += cnt[idx];
  }
  s[t] = sum;
  __syncthreads();
  for (int off = 128; off > 0; off >>= 1) {
    if (t < off) s[t] += s[t + off];
    __syncthreads();
  }
  if (t == 0) bsum[b] = s[0];
}

__global__ __launch_bounds__(256) void scan_bsum_kernel(int* __restrict__ bsum, int nb) {
  __shared__ int s[256];
  int t = threadIdx.x;
  int v = (t < nb) ? bsum[t] : 0;
  s[t] = v;
  __syncthreads();
  for (int off = 1; off < 256; off <<= 1) {
    int u = (t >= off) ? s[t - off] : 0;
    __syncthreads();
    s[t] += u;
    __syncthreads();
  }
  if (t < nb) bsum[t] = (t == 0) ? 0 : s[t - 1];
  if (t == 0) bsum[nb] = s[nb - 1];
}

__global__ __launch_bounds__(256) void scan_write_kernel(const int* __restrict__ cnt,
                                                         const int* __restrict__ bsum,
                                                         int* __restrict__ gscan) {
  __shared__ int s[256];
  int b = blockIdx.x, t = threadIdx.x;
  int base = b * SCAN_CHUNK + t * 16;
  int loc[16];
  int sum = 0;
#pragma unroll
  for (int i = 0; i < 16; ++i) {
    int idx = base + i;
    int v = (idx < CNT_TOT) ? cnt[idx] : 0;
    loc[i] = sum;
    sum += v;
  }
  s[t] = sum;
  __syncthreads();
  for (int off = 1; off < 256; off <<= 1) {
    int u = (t >= off) ? s[t - off] : 0;
    __syncthreads();
    s[t] += u;
    __syncthreads();
  }
  int toff = bsum[b] + ((t == 0) ? 0 : s[t - 1]);
#pragma unroll
  for (int i = 0; i < 16; ++i) {
    int idx = base + i;
    if (idx < CNT_TOT) gscan[idx] = toff + loc[i];
  }
  if (b == 0 && t == 0) gscan[CNT_TOT] = bsum[SCAN_BLOCKS];
}

// ---------- SAT dual (L0, L2): ONE traversal, no exp/max (expv precomputed per node) ----------
template <typename OutT>
__global__ __launch_bounds__(256) void sat_dual_z_kernel(
    const int* __restrict__ rowptr, const int* __restrict__ col,
    const float* __restrict__ ea, const __half* __restrict__ ha,
    const float* __restrict__ eb, const __half* __restrict__ hb,
    const float* __restrict__ pw, OutT* __restrict__ out, int n) {
  int row = blockIdx.x * 4 + (threadIdx.x >> 6);
  if (row >= n) return;
  int lane = threadIdx.x & 63;
  int p0 = rowptr[row], p1 = rowptr[row + 1];
  float za = 0.f, zb = 0.f, aa = 0.f, ab = 0.f;
  for (int p = p0; p < p1; ++p) {
    int c = col[p];
    float wa = ea[c], wb = eb[c];
    za += wa; zb += wb;
    aa += wa * __half2float(ha[(long long)c * 64 + lane]);
    ab += wb * __half2float(hb[(long long)c * 64 + lane]);
  }
  float r = (za > 0.f ? aa / za : 0.f) + (zb > 0.f ? ab / zb : 0.f);
  float pv = pw[0];
  r = r >= 0.f ? r : pv * r;   // prelu
  out[(long long)row * 64 + lane] = (OutT)r;
}

// ---------- H2t = H2 @ triW via f16 MFMA (no bias; trib added once per edge-row in mega) ----------
__global__ __launch_bounds__(256) void tri_mfma_kernel(
    const __half* __restrict__ H2, const __half* __restrict__ Wt,
    __half* __restrict__ H2t, int n) {
  const int tid = threadIdx.x;
  const int m0 = blockIdx.x * 64;
  const int wave = tid >> 6;
  const int lane = tid & 63;
  const int quad = lane >> 4;
  const int l16 = lane & 15;
  const int arow = m0 + wave * 16 + l16;
  f32x4 acc[4];
#pragma unroll
  for (int i = 0; i < 4; ++i) acc[i] = (f32x4){0.f, 0.f, 0.f, 0.f};
  const f16x8* Wf = (const f16x8*)Wt;
#pragma unroll
  for (int kc = 0; kc < 2; ++kc) {
    f16x8 af = (f16x8){0, 0, 0, 0, 0, 0, 0, 0};
    if (arow < n) af = *(const f16x8*)((const _Float16*)H2 + (long long)arow * 64 + kc * 32 + quad * 8);
#pragma unroll
    for (int nb = 0; nb < 4; ++nb) {
      f16x8 bf = Wf[(kc * 4 + nb) * 64 + lane];
      acc[nb] = __builtin_amdgcn_mfma_f32_16x16x32_f16(af, bf, acc[nb], 0, 0, 0);
    }
  }
#pragma unroll
  for (int nb = 0; nb < 4; ++nb) {
    int col = nb * 16 + l16;
#pragma unroll
    for (int reg = 0; reg < 4; ++reg) {
      int rg = m0 + wave * 16 + quad * 4 + reg;
      if (rg < n) H2t[(long long)rg * 64 + col] = __float2half(acc[nb][reg]);
    }
  }
}

// ---------- mega edge-row kernel: G = prelu(satL1a + satL1b) + trib + B2 @ H2t ----------
__global__ __launch_bounds__(256) void sat_l1_mega_kernel(
    const int* __restrict__ rp_a, const int* __restrict__ rp_b, const int* __restrict__ rp_B2,
    const int* __restrict__ pool,
    const float* __restrict__ ea, const __half* __restrict__ ha,
    const float* __restrict__ eb, const __half* __restrict__ hb,
    const __half* __restrict__ H2t, const float* __restrict__ trib,
    const float* __restrict__ pw, __half* __restrict__ G, int n) {
  int row = blockIdx.x * 4 + (threadIdx.x >> 6);
  if (row >= n) return;
  int lane = threadIdx.x & 63;
  // head a
  float za = 0.f, aa = 0.f;
  {
    int p0 = rp_a[row], p1 = rp_a[row + 1];
    for (int p = p0; p < p1; ++p) {
      int c = pool[p];
      float w = ea[c];
      za += w;
      aa += w * __half2float(ha[(long long)c * 64 + lane]);
    }
  }
  // head b
  float zb = 0.f, ab = 0.f;
  {
    int p0 = rp_b[row], p1 = rp_b[row + 1];
    for (int p = p0; p < p1; ++p) {
      int c = pool[p];
      float w = eb[c];
      zb += w;
      ab += w * __half2float(hb[(long long)c * 64 + lane]);
    }
  }
  float r = (za > 0.f ? aa / za : 0.f) + (zb > 0.f ? ab / zb : 0.f);
  float pv = pw[0];
  r = r >= 0.f ? r : pv * r;          // H1 = prelu(...)
  // Tm = B2 @ H2t + trib
  float tm = trib[lane];
  {
    int p0 = rp_B2[row], p1 = rp_B2[row + 1];
    for (int p = p0; p < p1; ++p) {
      int e = pool[p];
      int c = e / 3;
      float s = (e - 3 * c == 1) ? -1.f : 1.f;
      tm += s * __half2float(H2t[(long long)c * 64 + lane]);
    }
  }
  G[(long long)row * 64 + lane] = __float2half(r + tm);
}

// ---------- out = (H0 + B1 @ G) / 3 ----------
__global__ __launch_bounds__(256) void final_kernel(
    const int* __restrict__ rowptr, const int* __restrict__ ent,
    const float* __restrict__ H0, const __half* __restrict__ G,
    float* __restrict__ out, int n) {
  int row = blockIdx.x * 4 + (threadIdx.x >> 6);
  if (row >= n) return;
  int lane = threadIdx.x & 63;
  int p0 = rowptr[row], p1 = rowptr[row + 1];
  float acc = H0[(long long)row * 64 + lane];
  for (int p = p0; p < p1; ++p) {
    int e = ent[p];
    int c = e >> 1;
    float s = (e & 1) ? -1.f : 1.f;
    acc += s * __half2float(G[(long long)c * 64 + lane]);
  }
  out[(long long)row * 64 + lane] = acc * (1.0f / 3.0f);
}

extern "C" void kernel_launch(void* const* d_in, const int* in_sizes, int n_in,
                              void* d_out, int out_size, void* d_ws, size_t ws_size,
                              hipStream_t stream) {
  const float* X0 = (const float*)d_in[0];
  const int* E1 = (const int*)d_in[1];
  const int* T2 = (const int*)d_in[2];
  const int* L0i = (const int*)d_in[3];
  const int* L1ai = (const int*)d_in[4];
  const int* L1bi = (const int*)d_in[5];
  const int* L2i = (const int*)d_in[6];
  const int* B1i = (const int*)d_in[7];
  const int* B2i = (const int*)d_in[9];
  const float* W = (const float*)d_in[11];
  const float* bvec = (const float*)d_in[12];
  // a1_w/a1_b are mathematically dead: s1[r] cancels in the row softmax.
  const float* a2w = (const float*)d_in[15];
  const float* a2b = (const float*)d_in[16];
  const float* pw = (const float*)d_in[17];
  const float* triW = (const float*)d_in[18];
  const float* trib = (const float*)d_in[19];
  float* out = (float*)d_out;

  char* base = (char*)d_ws;
  size_t off = 0;
  auto alloc = [&](size_t bytes) -> void* {
    void* p = base + off;
    off += (bytes + 255) & ~(size_t)255;
    return p;
  };
  unsigned int* Xbit = (unsigned int*)alloc((size_t)N0 * 16 * 4);
  unsigned short* Bp = (unsigned short*)alloc((size_t)3 * 65536 * 2);
  __half* Wt = (__half*)alloc((size_t)4096 * 2);
  __half* h0 = (__half*)alloc((size_t)N0 * 64 * 2);
  __half* h1 = (__half*)alloc((size_t)N0 * 64 * 2);
  __half* h2 = (__half*)alloc((size_t)N1 * 64 * 2);
  __half* h3 = (__half*)alloc((size_t)N1 * 64 * 2);
  __half* h4 = (__half*)alloc((size_t)N2 * 64 * 2);
  __half* h5 = (__half*)alloc((size_t)N2 * 64 * 2);
  float* e0 = (float*)alloc((size_t)N0 * 4);
  float* e1 = (float*)alloc((size_t)N0 * 4);
  float* e2 = (float*)alloc((size_t)N1 * 4);
  float* e3 = (float*)alloc((size_t)N1 * 4);
  float* e4 = (float*)alloc((size_t)N2 * 4);
  float* e5 = (float*)alloc((size_t)N2 * 4);
  float* H0 = (float*)alloc((size_t)N0 * 64 * 4);
  __half* H2 = (__half*)alloc((size_t)N2 * 64 * 2);
  __half* H2t = (__half*)alloc((size_t)N2 * 64 * 2);
  __half* G = (__half*)alloc((size_t)N1 * 64 * 2);
  int* gscan = (int*)alloc((size_t)(CNT_TOT + 1) * 4);
  int* pool = (int*)alloc((size_t)TOT_E * 4);
  int* bsum = (int*)alloc((size_t)(SCAN_BLOCKS + 1) * 4);
  int* cntcur = (int*)alloc((size_t)2 * CNT_TOT * 4);   // cnt | cur, one memset
  int* cnt = cntcur;
  int* cur = cntcur + CNT_TOT;

  hipMemsetAsync(cntcur, 0, (size_t)2 * CNT_TOT * 4, stream);

  pack_bits_kernel<<<(N0 + 3) / 4, 256, 0, stream>>>(X0, Xbit);
  pack_w_kernel<<<(3 * 65536 + 255) / 256, 256, 0, stream>>>(W, Bp);
  pack_wt_kernel<<<16, 256, 0, stream>>>(triW, Wt);

  gemm_sat_kernel<1><<<(N0 + 255) / 256, 256, 0, stream>>>(Xbit, nullptr, Bp, bvec, a2w, a2b, 0, N0, h0, h1, e0, e1);
  gemm_sat_kernel<2><<<(N1 + 255) / 256, 256, 0, stream>>>(Xbit, E1, Bp + 65536, bvec, a2w, a2b, 2, N1, h2, h3, e2, e3);
  gemm_sat_kernel<3><<<(N2 + 255) / 256, 256, 0, stream>>>(Xbit, T2, Bp + 2 * 65536, bvec, a2w, a2b, 4, N2, h4, h5, e4, e5);

  count_all_kernel<<<(TOT_E + 255) / 256, 256, 0, stream>>>(L0i, L1ai, L1bi, L2i, B1i, B2i, cnt);
  scan_partial_kernel<<<SCAN_BLOCKS, 256, 0, stream>>>(cnt, bsum);
  scan_bsum_kernel<<<1, 256, 0, stream>>>(bsum, SCAN_BLOCKS);
  scan_write_kernel<<<SCAN_BLOCKS, 256, 0, stream>>>(cnt, bsum, gscan);
  fill_all_kernel<<<(TOT_E + 255) / 256, 256, 0, stream>>>(L0i, L1ai, L1bi, L2i, B1i, B2i, gscan, cur, pool);

  const int* rp0 = gscan + SEG_L0;
  const int* rp1a = gscan + SEG_L1A;
  const int* rp1b = gscan + SEG_L1B;
  const int* rp2 = gscan + SEG_L2;
  const int* rpB1 = gscan + SEG_B1;
  const int* rpB2 = gscan + SEG_B2;

  sat_dual_z_kernel<float><<<(N0 + 3) / 4, 256, 0, stream>>>(rp0, pool, e0, h0, e1, h1, pw, H0, N0);
  sat_dual_z_kernel<__half><<<(N2 + 3) / 4, 256, 0, stream>>>(rp2, pool, e4, h4, e5, h5, pw, H2, N2);
  tri_mfma_kernel<<<(N2 + 63) / 64, 256, 0, stream>>>(H2, Wt, H2t, N2);
  sat_l1_mega_kernel<<<(N1 + 3) / 4, 256, 0, stream>>>(rp1a, rp1b, rpB2, pool, e2, h2, e3, h3,
                                                       H2t, trib, pw, G, N1);
  final_kernel<<<(N0 + 3) / 4, 256, 0, stream>>>(rpB1, pool, H0, G, out, N0);
}

// Round 6
// 964.914 us; speedup vs baseline: 3.4907x; 1.1723x over previous
//
#include <hip/hip_runtime.h>
#include <hip/hip_fp16.h>

static constexpr int N0 = 50000;
static constexpr int N1 = 200000;
static constexpr int N2 = 100000;
static constexpr int NNZ0 = 600000;
static constexpr int NNZ1 = 1000000;
static constexpr int NNZ2 = 600000;
static constexpr int FIN = 500;

// concatenated count layout: [L0 | L1a | L1b | L2 | B1 | B2]
static constexpr int SEG_L0 = 0;
static constexpr int SEG_L1A = 50000;
static constexpr int SEG_L1B = 250000;
static constexpr int SEG_L2 = 450000;
static constexpr int SEG_B1 = 550000;
static constexpr int SEG_B2 = 600000;
static constexpr int CNT_TOT = 800000;
static constexpr int TOT_E = NNZ0 + NNZ1 + NNZ1 + NNZ2 + 2 * N1 + 3 * N2;  // 3.9M
static constexpr int SCAN_CHUNK = 4096;
static constexpr int SCAN_BLOCKS = (CNT_TOT + SCAN_CHUNK - 1) / SCAN_CHUNK;  // 196

typedef __attribute__((ext_vector_type(8))) short bf16x8;
typedef __attribute__((ext_vector_type(8))) _Float16 f16x8;
typedef __attribute__((ext_vector_type(4))) float f32x4;

__device__ __forceinline__ unsigned short f2bf(float f) {
  unsigned int b = __float_as_uint(f);
  b = (b + 0x7FFFu + ((b >> 16) & 1u)) >> 16;   // RNE
  return (unsigned short)b;
}

// ---------- pack X0 -> binary bitmasks: 512 bits = 16 uints per row (3.2 MB, L2-resident) ----------
__global__ __launch_bounds__(256) void pack_bits_kernel(const float* __restrict__ X0,
                                                        unsigned int* __restrict__ Xbit) {
  int row = blockIdx.x * 4 + (threadIdx.x >> 6);
  if (row >= N0) return;
  int lane = threadIdx.x & 63;
  const float* xr = X0 + (long long)row * FIN;
#pragma unroll
  for (int i = 0; i < 8; ++i) {
    int c = i * 64 + lane;
    bool pred = (c < FIN) && (xr[c] != 0.0f);
    unsigned long long m = __ballot(pred);
    if (lane == 0) {
      Xbit[row * 16 + 2 * i] = (unsigned int)m;
      Xbit[row * 16 + 2 * i + 1] = (unsigned int)(m >> 32);
    }
  }
}

// ---------- pack W -> bf16 MFMA B-fragment layout: [level][kc][nb][lane][j] ----------
__global__ void pack_w_kernel(const float* __restrict__ W, unsigned short* __restrict__ Bp) {
  int g = blockIdx.x * 256 + threadIdx.x;
  if (g >= 3 * 65536) return;
  int j = g & 7;
  int lane = (g >> 3) & 63;
  int nb = (g >> 9) & 7;
  int kc = (g >> 12) & 15;
  int level = g >> 16;
  int k = kc * 32 + (lane >> 4) * 8 + j;
  int col128 = nb * 16 + (lane & 15);
  int head = level * 2 + (col128 >> 6);
  int col = col128 & 63;
  float f = 0.0f;
  if (k < FIN) f = W[((long long)head * FIN + k) * 64 + col];
  Bp[g] = f2bf(f);
}

// ---------- pack triW -> f16 B-fragment layout: [kc(2)][nb(4)][lane][j] ----------
__global__ void pack_wt_kernel(const float* __restrict__ triW, __half* __restrict__ Wt) {
  int g = blockIdx.x * 256 + threadIdx.x;
  if (g >= 4096) return;
  int j = g & 7;
  int lane = (g >> 3) & 63;
  int nb = (g >> 9) & 3;
  int kc = g >> 11;
  int k = kc * 32 + (lane >> 4) * 8 + j;
  int col = nb * 16 + (lane & 15);
  Wt[g] = __float2half(triW[k * 64 + col]);
}

// ---------- fused bit-gather(AND) + in-register bf16 expansion + MFMA ----------
template <int NSRC>
__global__ __launch_bounds__(256) void gemm_sat_kernel(
    const unsigned int* __restrict__ Xbit, const int* __restrict__ srcidx,
    const unsigned short* __restrict__ Bp, const float* __restrict__ bvec,
    const float* __restrict__ a2w, const float* __restrict__ a2b, int head_lo,
    int M, __half* __restrict__ h_lo, __half* __restrict__ h_hi,
    float* __restrict__ e_lo, float* __restrict__ e_hi) {
  __shared__ __align__(16) unsigned int Sb[256 * 20];
  const int tid = threadIdx.x;
  const int m0 = blockIdx.x * 256;
  {
    int rg = m0 + tid;
    uint4 a[4];
#pragma unroll
    for (int c = 0; c < 4; ++c) a[c] = make_uint4(0u, 0u, 0u, 0u);
    if (rg < M) {
      if (NSRC == 1) {
        const uint4* up = (const uint4*)(Xbit + (long long)rg * 16);
#pragma unroll
        for (int c = 0; c < 4; ++c) a[c] = up[c];
      } else if (NSRC == 2) {
        const uint4* up = (const uint4*)(Xbit + (long long)srcidx[2 * rg + 0] * 16);
        const uint4* vp = (const uint4*)(Xbit + (long long)srcidx[2 * rg + 1] * 16);
#pragma unroll
        for (int c = 0; c < 4; ++c) {
          uint4 u = up[c], v = vp[c];
          a[c] = make_uint4(u.x & v.x, u.y & v.y, u.z & v.z, u.w & v.w);
        }
      } else {
        const uint4* up = (const uint4*)(Xbit + (long long)srcidx[3 * rg + 0] * 16);
        const uint4* vp = (const uint4*)(Xbit + (long long)srcidx[3 * rg + 1] * 16);
        const uint4* wp = (const uint4*)(Xbit + (long long)srcidx[3 * rg + 2] * 16);
#pragma unroll
        for (int c = 0; c < 4; ++c) {
          uint4 u = up[c], v = vp[c], w = wp[c];
          a[c] = make_uint4(u.x & v.x & w.x, u.y & v.y & w.y, u.z & v.z & w.z, u.w & v.w & w.w);
        }
      }
    }
#pragma unroll
    for (int c = 0; c < 4; ++c) *(uint4*)(Sb + tid * 20 + c * 4) = a[c];
  }
  __syncthreads();

  const int wave = tid >> 6;
  const int lane = tid & 63;
  const int quad = lane >> 4;
  const int l16 = lane & 15;
  f32x4 acc[8][4];   // [nb][sub]
#pragma unroll
  for (int i = 0; i < 8; ++i)
#pragma unroll
    for (int s = 0; s < 4; ++s) acc[i][s] = (f32x4){0.f, 0.f, 0.f, 0.f};
  const bf16x8* Bf = (const bf16x8*)Bp;
#pragma unroll 2
  for (int kc = 0; kc < 16; ++kc) {
    bf16x8 af[4];
#pragma unroll
    for (int sub = 0; sub < 4; ++sub) {
      unsigned int bw = Sb[(wave * 64 + sub * 16 + l16) * 20 + kc];
      unsigned int byte = (bw >> (quad * 8)) & 0xFFu;
#pragma unroll
      for (int j = 0; j < 4; ++j) {
        unsigned int b2 = (byte >> (2 * j)) & 3u;
        ((unsigned int*)&af[sub])[j] = ((b2 & 1u) | ((b2 & 2u) << 15)) * 0x3F80u;
      }
    }
#pragma unroll
    for (int nb = 0; nb < 8; ++nb) {
      bf16x8 bf = Bf[(kc * 8 + nb) * 64 + lane];
#pragma unroll
      for (int sub = 0; sub < 4; ++sub)
        acc[nb][sub] = __builtin_amdgcn_mfma_f32_16x16x32_bf16(af[sub], bf, acc[nb][sub], 0, 0, 0);
    }
  }

  float bia[8], aw[8];
#pragma unroll
  for (int nb = 0; nb < 8; ++nb) {
    int col128 = nb * 16 + l16;
    int hh = col128 >> 6, col = col128 & 63;
    bia[nb] = bvec[(head_lo + hh) * 64 + col];
    aw[nb] = a2w[(head_lo + hh) * 64 + col];
  }
  float blo = a2b[head_lo], bhi = a2b[head_lo + 1];
#pragma unroll
  for (int sub = 0; sub < 4; ++sub) {
    float plo[4] = {0.f, 0.f, 0.f, 0.f};
    float phi[4] = {0.f, 0.f, 0.f, 0.f};
#pragma unroll
    for (int nb = 0; nb < 8; ++nb) {
      int col128 = nb * 16 + l16;
      int hh = col128 >> 6, col = col128 & 63;
      __half* hdst = hh ? h_hi : h_lo;
#pragma unroll
      for (int reg = 0; reg < 4; ++reg) {
        int rg = m0 + wave * 64 + sub * 16 + quad * 4 + reg;   // C/D: row=quad*4+reg, col=l16
        float v = acc[nb][sub][reg] + bia[nb];
        if (rg < M) hdst[(long long)rg * 64 + col] = __float2half(v);
        if (hh) phi[reg] += v * aw[nb]; else plo[reg] += v * aw[nb];
      }
    }
#pragma unroll
    for (int off = 1; off < 16; off <<= 1) {
#pragma unroll
      for (int reg = 0; reg < 4; ++reg) {
        plo[reg] += __shfl_xor(plo[reg], off);
        phi[reg] += __shfl_xor(phi[reg], off);
      }
    }
    if (l16 == 0) {
#pragma unroll
      for (int reg = 0; reg < 4; ++reg) {
        int rg = m0 + wave * 64 + sub * 16 + quad * 4 + reg;
        if (rg < M) {
          e_lo[rg] = __expf(plo[reg] + blo);   // |s2| small by construction: no max needed
          e_hi[rg] = __expf(phi[reg] + bhi);
        }
      }
    }
  }
}

// ---------- merged CSR build ----------
__global__ __launch_bounds__(256) void count_all_kernel(
    const int* __restrict__ r0, const int* __restrict__ r1a, const int* __restrict__ r1b,
    const int* __restrict__ r2, const int* __restrict__ rb1, const int* __restrict__ rb2,
    int* __restrict__ cnt) {
  int g = blockIdx.x * 256 + threadIdx.x;
  if (g >= TOT_E) return;
  int seg, r;
  if (g < 600000) { seg = SEG_L0; r = r0[g]; }
  else if (g < 1600000) { seg = SEG_L1A; r = r1a[g - 600000]; }
  else if (g < 2600000) { seg = SEG_L1B; r = r1b[g - 1600000]; }
  else if (g < 3200000) { seg = SEG_L2; r = r2[g - 2600000]; }
  else if (g < 3600000) { seg = SEG_B1; r = rb1[g - 3200000]; }
  else { seg = SEG_B2; r = rb2[g - 3600000]; }
  atomicAdd(&cnt[seg + r], 1);
}

__global__ __launch_bounds__(256) void fill_all_kernel(
    const int* __restrict__ r0, const int* __restrict__ r1a, const int* __restrict__ r1b,
    const int* __restrict__ r2, const int* __restrict__ rb1, const int* __restrict__ rb2,
    const int* __restrict__ gscan, int* __restrict__ cur, int* __restrict__ pool) {
  int g = blockIdx.x * 256 + threadIdx.x;
  if (g >= TOT_E) return;
  int seg, r, val;
  if (g < 600000) { int l = g; seg = SEG_L0; r = r0[l]; val = r0[NNZ0 + l]; }
  else if (g < 1600000) { int l = g - 600000; seg = SEG_L1A; r = r1a[l]; val = r1a[NNZ1 + l]; }
  else if (g < 2600000) { int l = g - 1600000; seg = SEG_L1B; r = r1b[l]; val = r1b[NNZ1 + l]; }
  else if (g < 3200000) { int l = g - 2600000; seg = SEG_L2; r = r2[l]; val = r2[NNZ2 + l]; }
  else if (g < 3600000) { int l = g - 3200000; seg = SEG_B1; r = rb1[l]; val = l; }
  else { int l = g - 3600000; seg = SEG_B2; r = rb2[l]; val = l; }
  int pos = gscan[seg + r] + atomicAdd(&cur[seg + r], 1);
  pool[pos] = val;
}

__global__ __launch_bounds__(256) void scan_partial_kernel(const int* __restrict__ cnt,
                                                           int* __restrict__ bsum) {
  __shared__ int s[256];
  int b = blockIdx.x, t = threadIdx.x;
  int base = b * SCAN_CHUNK + t * 16;
  int sum = 0;
#pragma unroll
  for (int i = 0; i < 16; ++i) {
    int idx = base + i;
    if (idx < CNT_TOT) sum += cnt[idx];
  }
  s[t] = sum;
  __syncthreads();
  for (int off = 128; off > 0; off >>= 1) {
    if (t < off) s[t] += s[t + off];
    __syncthreads();
  }
  if (t == 0) bsum[b] = s[0];
}

__global__ __launch_bounds__(256) void scan_bsum_kernel(int* __restrict__ bsum, int nb) {
  __shared__ int s[256];
  int t = threadIdx.x;
  int v = (t < nb) ? bsum[t] : 0;
  s[t] = v;
  __syncthreads();
  for (int off = 1; off < 256; off <<= 1) {
    int u = (t >= off) ? s[t - off] : 0;
    __syncthreads();
    s[t] += u;
    __syncthreads();
  }
  if (t < nb) bsum[t] = (t == 0) ? 0 : s[t - 1];
  if (t == 0) bsum[nb] = s[nb - 1];
}

__global__ __launch_bounds__(256) void scan_write_kernel(const int* __restrict__ cnt,
                                                         const int* __restrict__ bsum,
                                                         int* __restrict__ gscan) {
  __shared__ int s[256];
  int b = blockIdx.x, t = threadIdx.x;
  int base = b * SCAN_CHUNK + t * 16;
  int loc[16];
  int sum = 0;
#pragma unroll
  for (int i = 0; i < 16; ++i) {
    int idx = base + i;
    int v = (idx < CNT_TOT) ? cnt[idx] : 0;
    loc[i] = sum;
    sum += v;
  }
  s[t] = sum;
  __syncthreads();
  for (int off = 1; off < 256; off <<= 1) {
    int u = (t >= off) ? s[t - off] : 0;
    __syncthreads();
    s[t] += u;
    __syncthreads();
  }
  int toff = bsum[b] + ((t == 0) ? 0 : s[t - 1]);
#pragma unroll
  for (int i = 0; i < 16; ++i) {
    int idx = base + i;
    if (idx < CNT_TOT) gscan[idx] = toff + loc[i];
  }
  if (b == 0 && t == 0) gscan[CNT_TOT] = bsum[SCAN_BLOCKS];
}

// ---------- dual-table gather over one CSR row, 4x unrolled for MLP ----------
__device__ __forceinline__ void dual_gather_row(
    const int* __restrict__ col, int p0, int p1, int lane,
    const float* __restrict__ ea, const __half* __restrict__ ha,
    const float* __restrict__ eb, const __half* __restrict__ hb,
    float& za, float& aa, float& zb, float& ab) {
  int p = p0;
  for (; p + 4 <= p1; p += 4) {
    int c0 = col[p + 0], c1 = col[p + 1], c2 = col[p + 2], c3 = col[p + 3];
    float wa0 = ea[c0], wa1 = ea[c1], wa2 = ea[c2], wa3 = ea[c3];
    float wb0 = eb[c0], wb1 = eb[c1], wb2 = eb[c2], wb3 = eb[c3];
    float va0 = __half2float(ha[(long long)c0 * 64 + lane]);
    float va1 = __half2float(ha[(long long)c1 * 64 + lane]);
    float va2 = __half2float(ha[(long long)c2 * 64 + lane]);
    float va3 = __half2float(ha[(long long)c3 * 64 + lane]);
    float vb0 = __half2float(hb[(long long)c0 * 64 + lane]);
    float vb1 = __half2float(hb[(long long)c1 * 64 + lane]);
    float vb2 = __half2float(hb[(long long)c2 * 64 + lane]);
    float vb3 = __half2float(hb[(long long)c3 * 64 + lane]);
    za += (wa0 + wa1) + (wa2 + wa3);
    zb += (wb0 + wb1) + (wb2 + wb3);
    aa += wa0 * va0 + wa1 * va1 + wa2 * va2 + wa3 * va3;
    ab += wb0 * vb0 + wb1 * vb1 + wb2 * vb2 + wb3 * vb3;
  }
  for (; p < p1; ++p) {
    int c = col[p];
    float wa = ea[c], wb = eb[c];
    za += wa; zb += wb;
    aa += wa * __half2float(ha[(long long)c * 64 + lane]);
    ab += wb * __half2float(hb[(long long)c * 64 + lane]);
  }
}

// ---------- SAT dual (L0, L2): one traversal, expv precomputed per node ----------
template <typename OutT>
__global__ __launch_bounds__(256) void sat_dual_z_kernel(
    const int* __restrict__ rowptr, const int* __restrict__ col,
    const float* __restrict__ ea, const __half* __restrict__ ha,
    const float* __restrict__ eb, const __half* __restrict__ hb,
    const float* __restrict__ pw, OutT* __restrict__ out, int n) {
  int row = blockIdx.x * 4 + (threadIdx.x >> 6);
  if (row >= n) return;
  int lane = threadIdx.x & 63;
  int p0 = rowptr[row], p1 = rowptr[row + 1];
  float za = 0.f, zb = 0.f, aa = 0.f, ab = 0.f;
  dual_gather_row(col, p0, p1, lane, ea, ha, eb, hb, za, aa, zb, ab);
  float r = (za > 0.f ? aa / za : 0.f) + (zb > 0.f ? ab / zb : 0.f);
  float pv = pw[0];
  r = r >= 0.f ? r : pv * r;   // prelu
  out[(long long)row * 64 + lane] = (OutT)r;
}

// ---------- H2t = H2 @ triW via f16 MFMA ----------
__global__ __launch_bounds__(256) void tri_mfma_kernel(
    const __half* __restrict__ H2, const __half* __restrict__ Wt,
    __half* __restrict__ H2t, int n) {
  const int tid = threadIdx.x;
  const int m0 = blockIdx.x * 64;
  const int wave = tid >> 6;
  const int lane = tid & 63;
  const int quad = lane >> 4;
  const int l16 = lane & 15;
  const int arow = m0 + wave * 16 + l16;
  f32x4 acc[4];
#pragma unroll
  for (int i = 0; i < 4; ++i) acc[i] = (f32x4){0.f, 0.f, 0.f, 0.f};
  const f16x8* Wf = (const f16x8*)Wt;
#pragma unroll
  for (int kc = 0; kc < 2; ++kc) {
    f16x8 af = (f16x8){0, 0, 0, 0, 0, 0, 0, 0};
    if (arow < n) af = *(const f16x8*)((const _Float16*)H2 + (long long)arow * 64 + kc * 32 + quad * 8);
#pragma unroll
    for (int nb = 0; nb < 4; ++nb) {
      f16x8 bf = Wf[(kc * 4 + nb) * 64 + lane];
      acc[nb] = __builtin_amdgcn_mfma_f32_16x16x32_f16(af, bf, acc[nb], 0, 0, 0);
    }
  }
#pragma unroll
  for (int nb = 0; nb < 4; ++nb) {
    int col = nb * 16 + l16;
#pragma unroll
    for (int reg = 0; reg < 4; ++reg) {
      int rg = m0 + wave * 16 + quad * 4 + reg;
      if (rg < n) H2t[(long long)rg * 64 + col] = __float2half(acc[nb][reg]);
    }
  }
}

// ---------- mega edge-row kernel: G = prelu(satL1a + satL1b) + trib + B2 @ H2t ----------
__global__ __launch_bounds__(256) void sat_l1_mega_kernel(
    const int* __restrict__ rp_a, const int* __restrict__ rp_b, const int* __restrict__ rp_B2,
    const int* __restrict__ pool,
    const float* __restrict__ ea, const __half* __restrict__ ha,
    const float* __restrict__ eb, const __half* __restrict__ hb,
    const __half* __restrict__ H2t, const float* __restrict__ trib,
    const float* __restrict__ pw, __half* __restrict__ G, int n) {
  int row = blockIdx.x * 4 + (threadIdx.x >> 6);
  if (row >= n) return;
  int lane = threadIdx.x & 63;
  // head a, 4x unrolled
  float za = 0.f, aa = 0.f;
  {
    int p0 = rp_a[row], p1 = rp_a[row + 1];
    int p = p0;
    for (; p + 4 <= p1; p += 4) {
      int c0 = pool[p + 0], c1 = pool[p + 1], c2 = pool[p + 2], c3 = pool[p + 3];
      float w0 = ea[c0], w1 = ea[c1], w2 = ea[c2], w3 = ea[c3];
      float v0 = __half2float(ha[(long long)c0 * 64 + lane]);
      float v1 = __half2float(ha[(long long)c1 * 64 + lane]);
      float v2 = __half2float(ha[(long long)c2 * 64 + lane]);
      float v3 = __half2float(ha[(long long)c3 * 64 + lane]);
      za += (w0 + w1) + (w2 + w3);
      aa += w0 * v0 + w1 * v1 + w2 * v2 + w3 * v3;
    }
    for (; p < p1; ++p) {
      int c = pool[p];
      float w = ea[c];
      za += w;
      aa += w * __half2float(ha[(long long)c * 64 + lane]);
    }
  }
  // head b, 4x unrolled
  float zb = 0.f, ab = 0.f;
  {
    int p0 = rp_b[row], p1 = rp_b[row + 1];
    int p = p0;
    for (; p + 4 <= p1; p += 4) {
      int c0 = pool[p + 0], c1 = pool[p + 1], c2 = pool[p + 2], c3 = pool[p + 3];
      float w0 = eb[c0], w1 = eb[c1], w2 = eb[c2], w3 = eb[c3];
      float v0 = __half2float(hb[(long long)c0 * 64 + lane]);
      float v1 = __half2float(hb[(long long)c1 * 64 + lane]);
      float v2 = __half2float(hb[(long long)c2 * 64 + lane]);
      float v3 = __half2float(hb[(long long)c3 * 64 + lane]);
      zb += (w0 + w1) + (w2 + w3);
      ab += w0 * v0 + w1 * v1 + w2 * v2 + w3 * v3;
    }
    for (; p < p1; ++p) {
      int c = pool[p];
      float w = eb[c];
      zb += w;
      ab += w * __half2float(hb[(long long)c * 64 + lane]);
    }
  }
  float r = (za > 0.f ? aa / za : 0.f) + (zb > 0.f ? ab / zb : 0.f);
  float pv = pw[0];
  r = r >= 0.f ? r : pv * r;          // H1 = prelu(...)
  // Tm = B2 @ H2t + trib (avg 1.5 entries/row; 2x unroll)
  float tm = trib[lane];
  {
    int p0 = rp_B2[row], p1 = rp_B2[row + 1];
    int p = p0;
    for (; p + 2 <= p1; p += 2) {
      int e0 = pool[p], e1 = pool[p + 1];
      int c0 = e0 / 3, c1 = e1 / 3;
      float s0 = (e0 - 3 * c0 == 1) ? -1.f : 1.f;
      float s1 = (e1 - 3 * c1 == 1) ? -1.f : 1.f;
      float v0 = __half2float(H2t[(long long)c0 * 64 + lane]);
      float v1 = __half2float(H2t[(long long)c1 * 64 + lane]);
      tm += s0 * v0 + s1 * v1;
    }
    for (; p < p1; ++p) {
      int e = pool[p];
      int c = e / 3;
      float s = (e - 3 * c == 1) ? -1.f : 1.f;
      tm += s * __half2float(H2t[(long long)c * 64 + lane]);
    }
  }
  G[(long long)row * 64 + lane] = __float2half(r + tm);
}

// ---------- out = (H0 + B1 @ G) / 3, B1 loop 4x unrolled ----------
__global__ __launch_bounds__(256) void final_kernel(
    const int* __restrict__ rowptr, const int* __restrict__ ent,
    const float* __restrict__ H0, const __half* __restrict__ G,
    float* __restrict__ out, int n) {
  int row = blockIdx.x * 4 + (threadIdx.x >> 6);
  if (row >= n) return;
  int lane = threadIdx.x & 63;
  int p0 = rowptr[row], p1 = rowptr[row + 1];
  float acc = H0[(long long)row * 64 + lane];
  int p = p0;
  for (; p + 4 <= p1; p += 4) {
    int e0 = ent[p], e1 = ent[p + 1], e2 = ent[p + 2], e3 = ent[p + 3];
    float s0 = (e0 & 1) ? -1.f : 1.f;
    float s1 = (e1 & 1) ? -1.f : 1.f;
    float s2 = (e2 & 1) ? -1.f : 1.f;
    float s3 = (e3 & 1) ? -1.f : 1.f;
    float v0 = __half2float(G[(long long)(e0 >> 1) * 64 + lane]);
    float v1 = __half2float(G[(long long)(e1 >> 1) * 64 + lane]);
    float v2 = __half2float(G[(long long)(e2 >> 1) * 64 + lane]);
    float v3 = __half2float(G[(long long)(e3 >> 1) * 64 + lane]);
    acc += s0 * v0 + s1 * v1 + s2 * v2 + s3 * v3;
  }
  for (; p < p1; ++p) {
    int e = ent[p];
    float s = (e & 1) ? -1.f : 1.f;
    acc += s * __half2float(G[(long long)(e >> 1) * 64 + lane]);
  }
  out[(long long)row * 64 + lane] = acc * (1.0f / 3.0f);
}

extern "C" void kernel_launch(void* const* d_in, const int* in_sizes, int n_in,
                              void* d_out, int out_size, void* d_ws, size_t ws_size,
                              hipStream_t stream) {
  const float* X0 = (const float*)d_in[0];
  const int* E1 = (const int*)d_in[1];
  const int* T2 = (const int*)d_in[2];
  const int* L0i = (const int*)d_in[3];
  const int* L1ai = (const int*)d_in[4];
  const int* L1bi = (const int*)d_in[5];
  const int* L2i = (const int*)d_in[6];
  const int* B1i = (const int*)d_in[7];
  const int* B2i = (const int*)d_in[9];
  const float* W = (const float*)d_in[11];
  const float* bvec = (const float*)d_in[12];
  // a1_w/a1_b are mathematically dead: s1[r] cancels in the row softmax.
  const float* a2w = (const float*)d_in[15];
  const float* a2b = (const float*)d_in[16];
  const float* pw = (const float*)d_in[17];
  const float* triW = (const float*)d_in[18];
  const float* trib = (const float*)d_in[19];
  float* out = (float*)d_out;

  char* base = (char*)d_ws;
  size_t off = 0;
  auto alloc = [&](size_t bytes) -> void* {
    void* p = base + off;
    off += (bytes + 255) & ~(size_t)255;
    return p;
  };
  unsigned int* Xbit = (unsigned int*)alloc((size_t)N0 * 16 * 4);
  unsigned short* Bp = (unsigned short*)alloc((size_t)3 * 65536 * 2);
  __half* Wt = (__half*)alloc((size_t)4096 * 2);
  __half* h0 = (__half*)alloc((size_t)N0 * 64 * 2);
  __half* h1 = (__half*)alloc((size_t)N0 * 64 * 2);
  __half* h2 = (__half*)alloc((size_t)N1 * 64 * 2);
  __half* h3 = (__half*)alloc((size_t)N1 * 64 * 2);
  __half* h4 = (__half*)alloc((size_t)N2 * 64 * 2);
  __half* h5 = (__half*)alloc((size_t)N2 * 64 * 2);
  float* e0 = (float*)alloc((size_t)N0 * 4);
  float* e1 = (float*)alloc((size_t)N0 * 4);
  float* e2 = (float*)alloc((size_t)N1 * 4);
  float* e3 = (float*)alloc((size_t)N1 * 4);
  float* e4 = (float*)alloc((size_t)N2 * 4);
  float* e5 = (float*)alloc((size_t)N2 * 4);
  float* H0 = (float*)alloc((size_t)N0 * 64 * 4);
  __half* H2 = (__half*)alloc((size_t)N2 * 64 * 2);
  __half* H2t = (__half*)alloc((size_t)N2 * 64 * 2);
  __half* G = (__half*)alloc((size_t)N1 * 64 * 2);
  int* gscan = (int*)alloc((size_t)(CNT_TOT + 1) * 4);
  int* pool = (int*)alloc((size_t)TOT_E * 4);
  int* bsum = (int*)alloc((size_t)(SCAN_BLOCKS + 1) * 4);
  int* cntcur = (int*)alloc((size_t)2 * CNT_TOT * 4);
  int* cnt = cntcur;
  int* cur = cntcur + CNT_TOT;

  hipMemsetAsync(cntcur, 0, (size_t)2 * CNT_TOT * 4, stream);

  pack_bits_kernel<<<(N0 + 3) / 4, 256, 0, stream>>>(X0, Xbit);
  pack_w_kernel<<<(3 * 65536 + 255) / 256, 256, 0, stream>>>(W, Bp);
  pack_wt_kernel<<<16, 256, 0, stream>>>(triW, Wt);

  gemm_sat_kernel<1><<<(N0 + 255) / 256, 256, 0, stream>>>(Xbit, nullptr, Bp, bvec, a2w, a2b, 0, N0, h0, h1, e0, e1);
  gemm_sat_kernel<2><<<(N1 + 255) / 256, 256, 0, stream>>>(Xbit, E1, Bp + 65536, bvec, a2w, a2b, 2, N1, h2, h3, e2, e3);
  gemm_sat_kernel<3><<<(N2 + 255) / 256, 256, 0, stream>>>(Xbit, T2, Bp + 2 * 65536, bvec, a2w, a2b, 4, N2, h4, h5, e4, e5);

  count_all_kernel<<<(TOT_E + 255) / 256, 256, 0, stream>>>(L0i, L1ai, L1bi, L2i, B1i, B2i, cnt);
  scan_partial_kernel<<<SCAN_BLOCKS, 256, 0, stream>>>(cnt, bsum);
  scan_bsum_kernel<<<1, 256, 0, stream>>>(bsum, SCAN_BLOCKS);
  scan_write_kernel<<<SCAN_BLOCKS, 256, 0, stream>>>(cnt, bsum, gscan);
  fill_all_kernel<<<(TOT_E + 255) / 256, 256, 0, stream>>>(L0i, L1ai, L1bi, L2i, B1i, B2i, gscan, cur, pool);

  const int* rp0 = gscan + SEG_L0;
  const int* rp1a = gscan + SEG_L1A;
  const int* rp1b = gscan + SEG_L1B;
  const int* rp2 = gscan + SEG_L2;
  const int* rpB1 = gscan + SEG_B1;
  const int* rpB2 = gscan + SEG_B2;

  sat_dual_z_kernel<float><<<(N0 + 3) / 4, 256, 0, stream>>>(rp0, pool, e0, h0, e1, h1, pw, H0, N0);
  sat_dual_z_kernel<__half><<<(N2 + 3) / 4, 256, 0, stream>>>(rp2, pool, e4, h4, e5, h5, pw, H2, N2);
  tri_mfma_kernel<<<(N2 + 63) / 64, 256, 0, stream>>>(H2, Wt, H2t, N2);
  sat_l1_mega_kernel<<<(N1 + 3) / 4, 256, 0, stream>>>(rp1a, rp1b, rpB2, pool, e2, h2, e3, h3,
                                                       H2t, trib, pw, G, N1);
  final_kernel<<<(N0 + 3) / 4, 256, 0, stream>>>(rpB1, pool, H0, G, out, N0);
}